// Round 6
// baseline (216.685 us; speedup 1.0000x reference)
//
#include <hip/hip_runtime.h>
#include <hip/hip_bf16.h>
#include <math.h>

#define NN     50000
#define FIN    128
#define F1     64      // H1*C1 = layer-1 output features
#define NH1    8
#define F2     64      // layer-2 output features

#define BSH    256                         // nodes per dst bucket (CSR build)
#define NB     ((NN + BSH - 1) / BSH)      // 196 buckets
#define BCAP   9472                        // per-bucket edge cap (mean 8448, +11 sigma)
#define PREB   13                          // swizzle blocks in k_front
#define MG1B   ((NN + 255) / 256)          // 196 mgemm1 super-blocks in k_mid

typedef __bf16 bf16x8 __attribute__((ext_vector_type(8)));
typedef float  f32x4  __attribute__((ext_vector_type(4)));
typedef float  f32x2  __attribute__((ext_vector_type(2)));
typedef unsigned short u16x8 __attribute__((ext_vector_type(8)));

// ---------------- runtime dtype helpers ----------------
// flags[0] = 1 if float tensors are fp32 (else bf16)
// flags[1] = 1 if edge_index is int64 (else int32)

__device__ __forceinline__ float loadF(const void* p, long long i, int fp32) {
    if (fp32) return ((const float*)p)[i];
    return __bfloat162float(((const __hip_bfloat16*)p)[i]);
}
__device__ __forceinline__ int loadI_nt(const void* p, long long i, int i64) {
    if (i64) return (int)__builtin_nontemporal_load(&((const long long*)p)[i]);
    return __builtin_nontemporal_load(&((const int*)p)[i]);
}
__device__ __forceinline__ unsigned short f2bfu(float f) {   // RNE f32->bf16 bits
    unsigned u = __float_as_uint(f);
    return (unsigned short)((u + 0x7FFFu + ((u >> 16) & 1u)) >> 16);
}
__device__ __forceinline__ float b2f(unsigned short u) {
    return __uint_as_float(((unsigned)u) << 16);
}

// ---------------- k_front: [sniff + W-swizzle] | [edge binning] (R15) ----------------

__global__ __launch_bounds__(1024) void k_front(
    const void* __restrict__ x, const void* __restrict__ ei, int E, int Etot,
    int* __restrict__ flags,
    const void* __restrict__ W1, const void* __restrict__ W2,
    unsigned short* __restrict__ W1p, unsigned short* __restrict__ W2p,
    int* __restrict__ bcnt, unsigned* __restrict__ binned) {
    __shared__ int s_a, s_b;
    __shared__ int hist[NB], gbase[NB];
    int tid = threadIdx.x;
    if (blockIdx.x < PREB) {
        if (tid == 0) { s_a = 0; s_b = 0; }
        __syncthreads();
        const unsigned short* u = (const unsigned short*)x;
        int cnt = 0;
        for (int i = tid; i < 8192; i += 1024) {
            unsigned short v = u[i];
            if ((v & 0x7F80) == 0x7F80) cnt++;     // bf16 Inf/NaN pattern
        }
        if (cnt) atomicAdd(&s_a, cnt);
        const unsigned* e32 = (const unsigned*)ei;
        int nz = 0;
        for (int i = tid; i < 2048; i += 1024) {
            if (e32[2 * i + 1] != 0u) nz++;        // high words if int64
        }
        if (nz) atomicAdd(&s_b, nz);
        __syncthreads();
        int fp32 = (s_a > 2) ? 1 : 0;
        if (tid == 0 && blockIdx.x == 0) {
            flags[0] = fp32;
            flags[1] = (s_b == 0) ? 1 : 0;
        }
        int gt = blockIdx.x * 1024 + tid, gs = PREB * 1024;
        for (int i = gt; i < (FIN / 32) * 4 * 512; i += gs) {   // 8192
            int j = i & 7, l = (i >> 3) & 63, f = i >> 9;
            int kb = f >> 2, nt = f & 3;
            int k = kb * 32 + (l >> 4) * 8 + j, n = nt * 16 + (l & 15);
            W1p[i] = f2bfu(loadF(W1, k * 64 + n, fp32));
        }
        for (int i = gt; i < (F1 / 32) * 4 * 512; i += gs) {    // 4096
            int j = i & 7, l = (i >> 3) & 63, f = i >> 9;
            int kb = f >> 2, nt = f & 3;
            int k = kb * 32 + (l >> 4) * 8 + j, n = nt * 16 + (l & 15);
            W2p[i] = f2bfu(loadF(W2, k * 64 + n, fp32));
        }
    } else {
        // ---- bin role (own int-width sniff) ----
        if (tid == 0) s_b = 0;
        for (int i = tid; i < NB; i += 1024) hist[i] = 0;
        __syncthreads();
        const unsigned* e32 = (const unsigned*)ei;
        int nz = 0;
        for (int i = tid; i < 2048; i += 1024) {
            if (e32[2 * i + 1] != 0u) nz++;
        }
        if (nz) atomicAdd(&s_b, nz);
        __syncthreads();
        int i64 = (s_b == 0) ? 1 : 0;
        long long base = (long long)(blockIdx.x - PREB) * 8192;
        unsigned pk[8]; short bb[8];
        #pragma unroll
        for (int u = 0; u < 8; ++u) {
            long long j = base + u * 1024 + tid;
            int s = -1, d = -1;
            if (j < Etot) {
                if (j < E) { s = loadI_nt(ei, j, i64); d = loadI_nt(ei, (long long)E + j, i64); }
                else       { s = d = (int)(j - E); }
            }
            if ((unsigned)s < NN && (unsigned)d < NN) {
                bb[u] = (short)(d >> 8);
                pk[u] = ((unsigned)s << 8) | (unsigned)(d & 255);
                atomicAdd(&hist[bb[u]], 1);
            } else bb[u] = -1;
        }
        __syncthreads();
        for (int i = tid; i < NB; i += 1024) {
            int h = hist[i];
            gbase[i] = h ? atomicAdd(&bcnt[i], h) : 0;
            hist[i] = 0;                             // reuse as local cursor
        }
        __syncthreads();
        #pragma unroll
        for (int u = 0; u < 8; ++u) {
            if (bb[u] >= 0) {
                int pos = gbase[bb[u]] + atomicAdd(&hist[bb[u]], 1);
                if (pos < BCAP) binned[(size_t)bb[u] * BCAP + pos] = pk[u];
            }
        }
    }
}

// ---------------- k_mid: [CSR counting sort] | [layer-1 MFMA GEMM] (R15) ----------------

__global__ __launch_bounds__(1024) void k_mid(
    const int* __restrict__ bcnt, const unsigned* __restrict__ binned,
    int* __restrict__ offs, int* __restrict__ perm,
    const void* __restrict__ x, const unsigned short* __restrict__ W1p,
    const void* __restrict__ attS, const void* __restrict__ attD,
    __hip_bfloat16* __restrict__ h1, float* __restrict__ a1s,
    float* __restrict__ a1d, const int* __restrict__ flags) {
    __shared__ __align__(16) char smem[33280];     // max(csr 3KB, mgemm 33KB)
    int tid = threadIdx.x;
    if (blockIdx.x < NB) {
        int* hist = (int*)smem;
        int* cur  = (int*)(smem + 1024);
        int* sd   = (int*)(smem + 2048);
        int bk = blockIdx.x;
        int n0 = bk * BSH;
        if (tid < 256) sd[tid] = (tid < NB) ? min(bcnt[tid], BCAP) : 0;
        __syncthreads();
        for (int off = 1; off < BSH; off <<= 1) {
            int t = 0;
            if (tid < 256 && tid >= off) t = sd[tid - off];
            __syncthreads();
            if (tid < 256) sd[tid] += t;
            __syncthreads();
        }
        int gb = (bk > 0) ? sd[bk - 1] : 0;
        if (bk == 0 && tid == 0) offs[NN] = sd[NB - 1];
        __syncthreads();
        int cnt = bcnt[bk]; if (cnt > BCAP) cnt = BCAP;
        const unsigned* bp = binned + (size_t)bk * BCAP;
        if (tid < 256) hist[tid] = 0;
        __syncthreads();
        for (int i = tid; i < cnt; i += 1024)
            atomicAdd(&hist[bp[i] & 255], 1);
        __syncthreads();
        int myh = (tid < 256) ? hist[tid] : 0;
        if (tid < 256) sd[tid] = myh;
        __syncthreads();
        for (int off = 1; off < BSH; off <<= 1) {
            int t = 0;
            if (tid < 256 && tid >= off) t = sd[tid - off];
            __syncthreads();
            if (tid < 256) sd[tid] += t;
            __syncthreads();
        }
        if (tid < 256) {
            int excl = sd[tid] - myh;
            cur[tid] = gb + excl;
            if (n0 + tid < NN) offs[n0 + tid] = gb + excl;
        }
        __syncthreads();
        for (int i = tid; i < cnt; i += 1024) {
            unsigned pk = bp[i];
            int pos = atomicAdd(&cur[pk & 255], 1);
            perm[pos] = (int)(pk >> 8);
        }
    } else {
        // ---- mgemm1 role: 4 sub-tiles of 64 nodes ----
        int fp32 = flags[0];
        unsigned short* hl = (unsigned short*)smem;          // 4 x 4096 ushort
        float* attSl = (float*)(smem + 32768);
        float* attDl = (float*)(smem + 32768 + 256);
        if (tid < 64) { attSl[tid] = loadF(attS, tid, fp32); attDl[tid] = loadF(attD, tid, fp32); }
        int sub = tid >> 8, t = tid & 255;
        int w = t >> 6, l = t & 63;
        int quad = l >> 4, lm = l & 15;
        int n0 = (blockIdx.x - NB) * 256 + sub * 64;
        unsigned short* hls = hl + sub * 4096;

        bf16x8 bfr[16];
        #pragma unroll
        for (int f = 0; f < 16; ++f)
            bfr[f] = *(const bf16x8*)(W1p + f * 512 + l * 8);

        int nodeA = n0 + w * 16 + lm;
        long long rowA = (nodeA < NN) ? nodeA : 0;     // clamp; garbage unused
        f32x4 acc[4];
        #pragma unroll
        for (int nt = 0; nt < 4; ++nt) acc[nt] = (f32x4){0.f, 0.f, 0.f, 0.f};

        #pragma unroll
        for (int kb = 0; kb < 4; ++kb) {
            bf16x8 af;
            if (!fp32) {
                af = *(const bf16x8*)((const unsigned short*)x + rowA * FIN + kb * 32 + quad * 8);
            } else {
                const float* xf = (const float*)x + rowA * FIN + kb * 32 + quad * 8;
                union { unsigned short s[8]; bf16x8 v; } tmp;
                #pragma unroll
                for (int j = 0; j < 8; ++j) tmp.s[j] = f2bfu(xf[j]);
                af = tmp.v;
            }
            #pragma unroll
            for (int nt = 0; nt < 4; ++nt)
                acc[nt] = __builtin_amdgcn_mfma_f32_16x16x32_bf16(af, bfr[kb * 4 + nt], acc[nt], 0, 0, 0);
        }

        #pragma unroll
        for (int nt = 0; nt < 4; ++nt) {
            #pragma unroll
            for (int r = 0; r < 4; ++r) {
                int nl = w * 16 + quad * 4 + r;
                int node = n0 + nl;
                int c = nt * 16 + lm;
                unsigned short hb = f2bfu(acc[nt][r]);
                hls[nl * 64 + c] = hb;
                if (node < NN) ((unsigned short*)h1)[(size_t)node * 64 + c] = hb;
            }
        }
        __syncthreads();
        // a1s/a1d per (node, head): 64 nodes x 8 heads = 512 pairs per sub
        #pragma unroll
        for (int pp = 0; pp < 2; ++pp) {
            int p = t + pp * 256;
            int nl = p >> 3, g = p & 7;
            int node = n0 + nl;
            float ss = 0.f, dd = 0.f;
            #pragma unroll
            for (int j = 0; j < 8; ++j) {
                float hv = b2f(hls[nl * 64 + g * 8 + j]);
                ss += hv * attSl[g * 8 + j];
                dd += hv * attDl[g * 8 + j];
            }
            if (node < NN) {
                a1s[(size_t)node * NH1 + g] = ss;
                a1d[(size_t)node * NH1 + g] = dd;
            }
        }
    }
}

// ---------------- Fused layer-1 agg + layer-2 GEMM + scalar projection ----------------
// R22: 4-dst interleaved aggregation (R21 with the stride bug fixed: edge
// cursors step by 8 = the number of edge slots per iteration; R21 stepped
// by 16 and silently dropped every odd 8-edge group -> absmax 7.9e-2).
// One iteration issues 4 perm + 4 a1s + 4 h1-dwordx4 = 12 independent
// loads (covering 8 edges x 4 dsts), ~2x the in-flight misses of R3's
// serial-dst loop. Rationale: measured ~1.8 TB/s ~= waves x misses x
// 128B / latency -> concurrency-bound. Clamped tails re-load perm[la_i]
// (same-address L2 hit, p=0 masked). __launch_bounds__(256,4) caps VGPR
// at 128 (state ~100).
// R18's head-half split REGRESSED (FETCH 90.7->104.5 MB): do not retry.
// R4's serial-dst sw-pipeline: compiler folded it away (null).

#define HLP 72

// per-dst MAC: acc[k] += p * unpack(hv)
#define MACB(At, Uv, pv) { \
    union { u16x8 v; unsigned u[4]; } U_; U_.v = Uv; \
    f32x2 P_ = (f32x2){pv, pv}; \
    _Pragma("unroll") \
    for (int k = 0; k < 4; ++k) { \
        f32x2 h_ = (f32x2){__uint_as_float(U_.u[k] << 16), \
                           __uint_as_float(U_.u[k] & 0xFFFF0000u)}; \
        At[k] = __builtin_elementwise_fma(P_, h_, At[k]); } }

// per-dst finish: cross-slot reduce, 1/den, +b1, ELU, write hl tile row
#define FIN(At, dnt, tt) { \
    float av_[8]; \
    _Pragma("unroll") \
    for (int k = 0; k < 4; ++k) { av_[2*k] = At[k].x; av_[2*k+1] = At[k].y; } \
    _Pragma("unroll") \
    for (int k = 0; k < 8; ++k) { \
        av_[k] += __shfl_xor(av_[k], 8, 64); \
        av_[k] += __shfl_xor(av_[k], 16, 64); \
        av_[k] += __shfl_xor(av_[k], 32, 64); } \
    float dn_ = dnt; \
    dn_ += __shfl_xor(dn_, 8, 64); \
    dn_ += __shfl_xor(dn_, 16, 64); \
    dn_ += __shfl_xor(dn_, 32, 64); \
    float rd_ = 1.f / (dn_ + 1e-16f); \
    if (g == 0) { \
        unsigned pk4_[4]; \
        _Pragma("unroll") \
        for (int k = 0; k < 4; ++k) { \
            float v0_ = fmaf(av_[2*k],   rd_, loadF(b1, q * 8 + 2*k,     fp32)); \
            float v1_ = fmaf(av_[2*k+1], rd_, loadF(b1, q * 8 + 2*k + 1, fp32)); \
            v0_ = (v0_ > 0.f) ? v0_ : expm1f(v0_); \
            v1_ = (v1_ > 0.f) ? v1_ : expm1f(v1_); \
            pk4_[k] = (unsigned)f2bfu(v0_) | ((unsigned)f2bfu(v1_) << 16); } \
        *(uint4*)&hl[(w * 4 + tt) * HLP + q * 8] = \
            make_uint4(pk4_[0], pk4_[1], pk4_[2], pk4_[3]); } }

__global__ __launch_bounds__(256, 4) void k_agg1f(
    const int* __restrict__ offs, const int* __restrict__ perm,
    const __hip_bfloat16* __restrict__ h1, const float* __restrict__ a1s,
    const float* __restrict__ a1d, const void* __restrict__ b1,
    const unsigned short* __restrict__ W2p,
    const void* __restrict__ attS2, const void* __restrict__ attD2,
    const void* __restrict__ linW,
    float2* __restrict__ g2s, float* __restrict__ a2d,
    int n, const int* __restrict__ flags) {
    int fp32 = flags[0];
    __shared__ __align__(16) unsigned short hl[16 * HLP];   // 2.25 KB helu tile (bf16 bits)
    __shared__ float attSl[64], attDl[64];
    __shared__ float sp[16 * 4], dp[16 * 4], gp[16 * 4];
    int tid = threadIdx.x;
    if (tid < 64) { attSl[tid] = loadF(attS2, tid, fp32); attDl[tid] = loadF(attD2, tid, fp32); }
    int w = tid >> 6, c = tid & 63;
    int n0 = blockIdx.x * 16;
    const unsigned short* hu = (const unsigned short*)h1;

    // ---- phase 1: 4-dst interleaved, 8-edge x 8-lane per dst ----
    // grid is exact: n == NN == 50000 = 3125 blocks * 16, so all 4 dsts valid
    int g = c >> 3, q = c & 7;
    int d0 = n0 + w * 4;
    int o0 = offs[d0], o1 = offs[d0 + 1], o2 = offs[d0 + 2],
        o3 = offs[d0 + 3], o4 = offs[d0 + 4];
    int la0 = o1 - 1, la1 = o2 - 1, la2 = o3 - 1, la3 = o4 - 1;
    int bt0 = o0 + g, bt1 = o1 + g, bt2 = o2 + g, bt3 = o3 + g;
    float ad0 = a1d[(size_t)d0 * NH1 + q];
    float ad1 = a1d[(size_t)(d0 + 1) * NH1 + q];
    float ad2 = a1d[(size_t)(d0 + 2) * NH1 + q];
    float ad3 = a1d[(size_t)(d0 + 3) * NH1 + q];
    f32x2 A0[4], A1[4], A2[4], A3[4];
    #pragma unroll
    for (int k = 0; k < 4; ++k) {
        A0[k] = (f32x2){0.f, 0.f}; A1[k] = (f32x2){0.f, 0.f};
        A2[k] = (f32x2){0.f, 0.f}; A3[k] = (f32x2){0.f, 0.f};
    }
    float dn0 = 0.f, dn1 = 0.f, dn2 = 0.f, dn3 = 0.f;

    int maxlen = max(max(o1 - o0, o2 - o1), max(o3 - o2, o4 - o3));
    int niter = (maxlen + 7) >> 3;          // 8 edge slots per dst per iter

    for (int it = 0; it < niter; ++it) {
        int j0 = bt0, j1 = bt1, j2 = bt2, j3 = bt3;
        bt0 += 8; bt1 += 8; bt2 += 8; bt3 += 8;
        // batch-issue: 4 perm, then 4 a1s + 4 h1 (12 independent streams)
        int s0 = perm[min(j0, la0)];
        int s1 = perm[min(j1, la1)];
        int s2 = perm[min(j2, la2)];
        int s3 = perm[min(j3, la3)];
        float w0 = a1s[(size_t)s0 * NH1 + q];
        float w1 = a1s[(size_t)s1 * NH1 + q];
        float w2 = a1s[(size_t)s2 * NH1 + q];
        float w3 = a1s[(size_t)s3 * NH1 + q];
        u16x8 v0 = *(const u16x8*)(hu + (size_t)s0 * 64 + q * 8);
        u16x8 v1 = *(const u16x8*)(hu + (size_t)s1 * 64 + q * 8);
        u16x8 v2 = *(const u16x8*)(hu + (size_t)s2 * 64 + q * 8);
        u16x8 v3 = *(const u16x8*)(hu + (size_t)s3 * 64 + q * 8);
        // p per dst
        float e0 = w0 + ad0; e0 = fmaxf(e0, 0.2f * e0);
        float p0 = (j0 <= la0) ? __expf(e0) : 0.f; dn0 += p0;
        float e1 = w1 + ad1; e1 = fmaxf(e1, 0.2f * e1);
        float p1 = (j1 <= la1) ? __expf(e1) : 0.f; dn1 += p1;
        float e2 = w2 + ad2; e2 = fmaxf(e2, 0.2f * e2);
        float p2 = (j2 <= la2) ? __expf(e2) : 0.f; dn2 += p2;
        float e3 = w3 + ad3; e3 = fmaxf(e3, 0.2f * e3);
        float p3 = (j3 <= la3) ? __expf(e3) : 0.f; dn3 += p3;
        // MACs
        MACB(A0, v0, p0)
        MACB(A1, v1, p1)
        MACB(A2, v2, p2)
        MACB(A3, v3, p3)
    }

    FIN(A0, dn0, 0)
    FIN(A1, dn1, 1)
    FIN(A2, dn2, 2)
    FIN(A3, dn3, 3)
    __syncthreads();

    // ---- phase 2: h2 tile = hl @ W2 (wave w = col-tile w); g2/a2s/a2d epilogue ----
    int quad = c >> 4, lm = c & 15;
    bf16x8 bf0 = *(const bf16x8*)(W2p + (0 * 4 + w) * 512 + c * 8);
    bf16x8 bf1 = *(const bf16x8*)(W2p + (1 * 4 + w) * 512 + c * 8);
    bf16x8 af0 = *(const bf16x8*)(hl + lm * HLP + 0 * 32 + quad * 8);
    bf16x8 af1 = *(const bf16x8*)(hl + lm * HLP + 1 * 32 + quad * 8);
    f32x4 acc2 = (f32x4){0.f, 0.f, 0.f, 0.f};
    acc2 = __builtin_amdgcn_mfma_f32_16x16x32_bf16(af0, bf0, acc2, 0, 0, 0);
    acc2 = __builtin_amdgcn_mfma_f32_16x16x32_bf16(af1, bf1, acc2, 0, 0, 0);

    int cg = w * 16 + lm;                                // global output col
    float aSc = attSl[cg], aDc = attDl[cg];
    float lWc = loadF(linW, cg, fp32);
    #pragma unroll
    for (int r = 0; r < 4; ++r) {
        int nl = quad * 4 + r;
        unsigned short hb = f2bfu(acc2[r]);              // same rounding as before
        float hv = b2f(hb);
        float pvs = hv * aSc, pvd = hv * aDc, pvg = hv * lWc;
        pvs += __shfl_xor(pvs, 1, 64); pvd += __shfl_xor(pvd, 1, 64); pvg += __shfl_xor(pvg, 1, 64);
        pvs += __shfl_xor(pvs, 2, 64); pvd += __shfl_xor(pvd, 2, 64); pvg += __shfl_xor(pvg, 2, 64);
        pvs += __shfl_xor(pvs, 4, 64); pvd += __shfl_xor(pvd, 4, 64); pvg += __shfl_xor(pvg, 4, 64);
        pvs += __shfl_xor(pvs, 8, 64); pvd += __shfl_xor(pvd, 8, 64); pvg += __shfl_xor(pvg, 8, 64);
        if (lm == 0) { sp[nl * 4 + w] = pvs; dp[nl * 4 + w] = pvd; gp[nl * 4 + w] = pvg; }
    }
    __syncthreads();
    if (tid < 16) {
        int node = n0 + tid;
        if (node < n) {
            float ss = sp[tid * 4 + 0] + sp[tid * 4 + 1] + sp[tid * 4 + 2] + sp[tid * 4 + 3];
            float dd = dp[tid * 4 + 0] + dp[tid * 4 + 1] + dp[tid * 4 + 2] + dp[tid * 4 + 3];
            float gg = gp[tid * 4 + 0] + gp[tid * 4 + 1] + gp[tid * 4 + 2] + gp[tid * 4 + 3];
            g2s[node] = make_float2(ss, gg);
            a2d[node] = dd;
        }
    }
}

// ---------------- Layer 2 aggregation, scalar form ----------------
// out[d] = sum_e p_e * g2[s_e] / den + (b2·linW + linb). Per edge: one perm
// read + one 8B gather + ~6 VALU; lanes work disjoint edges.

__global__ __launch_bounds__(256) void k_agg2(
    const int* __restrict__ offs, const int* __restrict__ perm,
    const float2* __restrict__ g2s, const float* __restrict__ a2d,
    const void* __restrict__ b2, const void* __restrict__ linW,
    const void* __restrict__ linb,
    void* __restrict__ out, int n, const int* __restrict__ flags) {
    int fp32 = flags[0];
    int w = threadIdx.x >> 6, c = threadIdx.x & 63;
    int d = blockIdx.x * 4 + w;
    if (d >= n) return;
    int start = offs[d], end = offs[d + 1];
    float ad = a2d[d];
    float acc = 0.f, den = 0.f;
    for (int i = start + c; i < end; i += 64) {
        int s = perm[i];
        float2 ag = g2s[s];
        float e = ag.x + ad;
        e = fmaxf(e, 0.2f * e);                      // leaky_relu(0.2)
        float p = __expf(e);
        acc = fmaf(p, ag.y, acc);
        den += p;
    }
    float cst = loadF(b2, c, fp32) * loadF(linW, c, fp32);   // b2·linW partial
    #pragma unroll
    for (int off = 1; off < 64; off <<= 1) {
        acc += __shfl_xor(acc, off, 64);
        den += __shfl_xor(den, off, 64);
        cst += __shfl_xor(cst, off, 64);
    }
    if (c == 0) {
        float r = acc / (den + 1e-16f) + cst + loadF(linb, 0, fp32);
        if (fp32) ((float*)out)[d] = r;
        else      ((__hip_bfloat16*)out)[d] = __float2bfloat16(r);
    }
}

// ---------------- host launcher ----------------

static inline char* carve(char*& p, size_t bytes) {
    char* r = p;
    p += (bytes + 255) & ~size_t(255);
    return r;
}

extern "C" void kernel_launch(void* const* d_in, const int* in_sizes, int n_in,
                              void* d_out, int out_size, void* d_ws, size_t ws_size,
                              hipStream_t stream) {
    const void* x     = d_in[0];
    const void* ei    = d_in[1];
    const void* W1    = d_in[2];
    const void* attS1 = d_in[3];
    const void* attD1 = d_in[4];
    const void* b1    = d_in[5];
    const void* W2    = d_in[6];
    const void* attS2 = d_in[7];
    const void* attD2 = d_in[8];
    const void* b2    = d_in[9];
    const void* linW  = d_in[10];
    const void* linb  = d_in[11];

    int E    = in_sizes[1] / 2;
    int Etot = E + NN;

    // workspace layout (~25 MB)
    char* p = (char*)d_ws;
    int*   flags = (int*)carve(p, 256);
    int*   bcnt  = (int*)carve(p, (size_t)NB * 4);
    unsigned short* W1p = (unsigned short*)carve(p, 8192 * 2);
    unsigned short* W2p = (unsigned short*)carve(p, 4096 * 2);
    int*   offs  = (int*)carve(p, (size_t)(NN + 1) * 4);       // 200 KB
    int*   perm  = (int*)carve(p, (size_t)Etot * 4);           // 6.6 MB
    // binned has its own region (k_mid overlaps csr reads with mgemm writes)
    unsigned* binned = (unsigned*)carve(p, (size_t)NB * BCAP * 4);  // 7.43 MB
    float*    a1s    = (float*)carve(p, (size_t)NN * NH1 * 4);      // 1.6 MB
    float*    a1d    = (float*)carve(p, (size_t)NN * NH1 * 4);      // 1.6 MB
    __hip_bfloat16* h1 = (__hip_bfloat16*)carve(p, (size_t)NN * F1 * 2);  // 6.4 MB
    float2* g2s = (float2*)carve(p, (size_t)NN * 8);           // 400 KB (a2s, g2)
    float*  a2d = (float*)carve(p, (size_t)NN * 4);            // 200 KB

    hipMemsetAsync(bcnt, 0, (size_t)NB * 4, stream);

    int nbin = (Etot + 8191) / 8192;
    k_front<<<PREB + nbin, 1024, 0, stream>>>(x, ei, E, Etot, flags,
                                              W1, W2, W1p, W2p, bcnt, binned);
    k_mid<<<NB + MG1B, 1024, 0, stream>>>(bcnt, binned, offs, perm,
                                          x, W1p, attS1, attD1, h1, a1s, a1d, flags);
    k_agg1f<<<(NN + 15) / 16, 256, 0, stream>>>(offs, perm, h1, a1s, a1d, b1,
                                                W2p, attS2, attD2, linW, g2s, a2d, NN, flags);
    k_agg2<<<(NN + 3) / 4, 256, 0, stream>>>(offs, perm, g2s, a2d, b2, linW, linb, d_out, NN, flags);
}

// Round 7
// 204.248 us; speedup vs baseline: 1.0609x; 1.0609x over previous
//
#include <hip/hip_runtime.h>
#include <hip/hip_bf16.h>
#include <math.h>

#define NN     50000
#define FIN    128
#define F1     64      // H1*C1 = layer-1 output features
#define NH1    8
#define F2     64      // layer-2 output features

#define BSH    256                         // nodes per dst bucket (CSR build)
#define NB     ((NN + BSH - 1) / BSH)      // 196 buckets
#define BCAP   9472                        // per-bucket edge cap (mean 8448, +11 sigma)
#define PREB   13                          // swizzle blocks in k_front
#define MG1B   ((NN + 255) / 256)          // 196 mgemm1 super-blocks in k_mid

typedef __bf16 bf16x8 __attribute__((ext_vector_type(8)));
typedef float  f32x4  __attribute__((ext_vector_type(4)));
typedef unsigned short u16x8 __attribute__((ext_vector_type(8)));

// ---------------- runtime dtype helpers ----------------
// flags[0] = 1 if float tensors are fp32 (else bf16)
// flags[1] = 1 if edge_index is int64 (else int32)

__device__ __forceinline__ float loadF(const void* p, long long i, int fp32) {
    if (fp32) return ((const float*)p)[i];
    return __bfloat162float(((const __hip_bfloat16*)p)[i]);
}
__device__ __forceinline__ int loadI_nt(const void* p, long long i, int i64) {
    if (i64) return (int)__builtin_nontemporal_load(&((const long long*)p)[i]);
    return __builtin_nontemporal_load(&((const int*)p)[i]);
}
__device__ __forceinline__ unsigned short f2bfu(float f) {   // RNE f32->bf16 bits
    unsigned u = __float_as_uint(f);
    return (unsigned short)((u + 0x7FFFu + ((u >> 16) & 1u)) >> 16);
}
__device__ __forceinline__ float b2f(unsigned short u) {
    return __uint_as_float(((unsigned)u) << 16);
}

// ---------------- k_front: [sniff + W-swizzle] | [edge binning] (R15) ----------------

__global__ __launch_bounds__(1024) void k_front(
    const void* __restrict__ x, const void* __restrict__ ei, int E, int Etot,
    int* __restrict__ flags,
    const void* __restrict__ W1, const void* __restrict__ W2,
    unsigned short* __restrict__ W1p, unsigned short* __restrict__ W2p,
    int* __restrict__ bcnt, unsigned* __restrict__ binned) {
    __shared__ int s_a, s_b;
    __shared__ int hist[NB], gbase[NB];
    int tid = threadIdx.x;
    if (blockIdx.x < PREB) {
        if (tid == 0) { s_a = 0; s_b = 0; }
        __syncthreads();
        const unsigned short* u = (const unsigned short*)x;
        int cnt = 0;
        for (int i = tid; i < 8192; i += 1024) {
            unsigned short v = u[i];
            if ((v & 0x7F80) == 0x7F80) cnt++;     // bf16 Inf/NaN pattern
        }
        if (cnt) atomicAdd(&s_a, cnt);
        const unsigned* e32 = (const unsigned*)ei;
        int nz = 0;
        for (int i = tid; i < 2048; i += 1024) {
            if (e32[2 * i + 1] != 0u) nz++;        // high words if int64
        }
        if (nz) atomicAdd(&s_b, nz);
        __syncthreads();
        int fp32 = (s_a > 2) ? 1 : 0;
        if (tid == 0 && blockIdx.x == 0) {
            flags[0] = fp32;
            flags[1] = (s_b == 0) ? 1 : 0;
        }
        int gt = blockIdx.x * 1024 + tid, gs = PREB * 1024;
        for (int i = gt; i < (FIN / 32) * 4 * 512; i += gs) {   // 8192
            int j = i & 7, l = (i >> 3) & 63, f = i >> 9;
            int kb = f >> 2, nt = f & 3;
            int k = kb * 32 + (l >> 4) * 8 + j, n = nt * 16 + (l & 15);
            W1p[i] = f2bfu(loadF(W1, k * 64 + n, fp32));
        }
        for (int i = gt; i < (F1 / 32) * 4 * 512; i += gs) {    // 4096
            int j = i & 7, l = (i >> 3) & 63, f = i >> 9;
            int kb = f >> 2, nt = f & 3;
            int k = kb * 32 + (l >> 4) * 8 + j, n = nt * 16 + (l & 15);
            W2p[i] = f2bfu(loadF(W2, k * 64 + n, fp32));
        }
    } else {
        // ---- bin role (own int-width sniff) ----
        if (tid == 0) s_b = 0;
        for (int i = tid; i < NB; i += 1024) hist[i] = 0;
        __syncthreads();
        const unsigned* e32 = (const unsigned*)ei;
        int nz = 0;
        for (int i = tid; i < 2048; i += 1024) {
            if (e32[2 * i + 1] != 0u) nz++;
        }
        if (nz) atomicAdd(&s_b, nz);
        __syncthreads();
        int i64 = (s_b == 0) ? 1 : 0;
        long long base = (long long)(blockIdx.x - PREB) * 8192;
        unsigned pk[8]; short bb[8];
        #pragma unroll
        for (int u = 0; u < 8; ++u) {
            long long j = base + u * 1024 + tid;
            int s = -1, d = -1;
            if (j < Etot) {
                if (j < E) { s = loadI_nt(ei, j, i64); d = loadI_nt(ei, (long long)E + j, i64); }
                else       { s = d = (int)(j - E); }
            }
            if ((unsigned)s < NN && (unsigned)d < NN) {
                bb[u] = (short)(d >> 8);
                pk[u] = ((unsigned)s << 8) | (unsigned)(d & 255);
                atomicAdd(&hist[bb[u]], 1);
            } else bb[u] = -1;
        }
        __syncthreads();
        for (int i = tid; i < NB; i += 1024) {
            int h = hist[i];
            gbase[i] = h ? atomicAdd(&bcnt[i], h) : 0;
            hist[i] = 0;                             // reuse as local cursor
        }
        __syncthreads();
        #pragma unroll
        for (int u = 0; u < 8; ++u) {
            if (bb[u] >= 0) {
                int pos = gbase[bb[u]] + atomicAdd(&hist[bb[u]], 1);
                if (pos < BCAP) binned[(size_t)bb[u] * BCAP + pos] = pk[u];
            }
        }
    }
}

// ---------------- k_mid: [CSR counting sort] | [layer-1 MFMA GEMM] (R15) ----------------

__global__ __launch_bounds__(1024) void k_mid(
    const int* __restrict__ bcnt, const unsigned* __restrict__ binned,
    int* __restrict__ offs, int* __restrict__ perm,
    const void* __restrict__ x, const unsigned short* __restrict__ W1p,
    const void* __restrict__ attS, const void* __restrict__ attD,
    __hip_bfloat16* __restrict__ h1, float* __restrict__ a1s,
    float* __restrict__ a1d, const int* __restrict__ flags) {
    __shared__ __align__(16) char smem[33280];     // max(csr 3KB, mgemm 33KB)
    int tid = threadIdx.x;
    if (blockIdx.x < NB) {
        int* hist = (int*)smem;
        int* cur  = (int*)(smem + 1024);
        int* sd   = (int*)(smem + 2048);
        int bk = blockIdx.x;
        int n0 = bk * BSH;
        if (tid < 256) sd[tid] = (tid < NB) ? min(bcnt[tid], BCAP) : 0;
        __syncthreads();
        for (int off = 1; off < BSH; off <<= 1) {
            int t = 0;
            if (tid < 256 && tid >= off) t = sd[tid - off];
            __syncthreads();
            if (tid < 256) sd[tid] += t;
            __syncthreads();
        }
        int gb = (bk > 0) ? sd[bk - 1] : 0;
        if (bk == 0 && tid == 0) offs[NN] = sd[NB - 1];
        __syncthreads();
        int cnt = bcnt[bk]; if (cnt > BCAP) cnt = BCAP;
        const unsigned* bp = binned + (size_t)bk * BCAP;
        if (tid < 256) hist[tid] = 0;
        __syncthreads();
        for (int i = tid; i < cnt; i += 1024)
            atomicAdd(&hist[bp[i] & 255], 1);
        __syncthreads();
        int myh = (tid < 256) ? hist[tid] : 0;
        if (tid < 256) sd[tid] = myh;
        __syncthreads();
        for (int off = 1; off < BSH; off <<= 1) {
            int t = 0;
            if (tid < 256 && tid >= off) t = sd[tid - off];
            __syncthreads();
            if (tid < 256) sd[tid] += t;
            __syncthreads();
        }
        if (tid < 256) {
            int excl = sd[tid] - myh;
            cur[tid] = gb + excl;
            if (n0 + tid < NN) offs[n0 + tid] = gb + excl;
        }
        __syncthreads();
        for (int i = tid; i < cnt; i += 1024) {
            unsigned pk = bp[i];
            int pos = atomicAdd(&cur[pk & 255], 1);
            perm[pos] = (int)(pk >> 8);
        }
    } else {
        // ---- mgemm1 role: 4 sub-tiles of 64 nodes ----
        int fp32 = flags[0];
        unsigned short* hl = (unsigned short*)smem;          // 4 x 4096 ushort
        float* attSl = (float*)(smem + 32768);
        float* attDl = (float*)(smem + 32768 + 256);
        if (tid < 64) { attSl[tid] = loadF(attS, tid, fp32); attDl[tid] = loadF(attD, tid, fp32); }
        int sub = tid >> 8, t = tid & 255;
        int w = t >> 6, l = t & 63;
        int quad = l >> 4, lm = l & 15;
        int n0 = (blockIdx.x - NB) * 256 + sub * 64;
        unsigned short* hls = hl + sub * 4096;

        bf16x8 bfr[16];
        #pragma unroll
        for (int f = 0; f < 16; ++f)
            bfr[f] = *(const bf16x8*)(W1p + f * 512 + l * 8);

        int nodeA = n0 + w * 16 + lm;
        long long rowA = (nodeA < NN) ? nodeA : 0;     // clamp; garbage unused
        f32x4 acc[4];
        #pragma unroll
        for (int nt = 0; nt < 4; ++nt) acc[nt] = (f32x4){0.f, 0.f, 0.f, 0.f};

        #pragma unroll
        for (int kb = 0; kb < 4; ++kb) {
            bf16x8 af;
            if (!fp32) {
                af = *(const bf16x8*)((const unsigned short*)x + rowA * FIN + kb * 32 + quad * 8);
            } else {
                const float* xf = (const float*)x + rowA * FIN + kb * 32 + quad * 8;
                union { unsigned short s[8]; bf16x8 v; } tmp;
                #pragma unroll
                for (int j = 0; j < 8; ++j) tmp.s[j] = f2bfu(xf[j]);
                af = tmp.v;
            }
            #pragma unroll
            for (int nt = 0; nt < 4; ++nt)
                acc[nt] = __builtin_amdgcn_mfma_f32_16x16x32_bf16(af, bfr[kb * 4 + nt], acc[nt], 0, 0, 0);
        }

        #pragma unroll
        for (int nt = 0; nt < 4; ++nt) {
            #pragma unroll
            for (int r = 0; r < 4; ++r) {
                int nl = w * 16 + quad * 4 + r;
                int node = n0 + nl;
                int c = nt * 16 + lm;
                unsigned short hb = f2bfu(acc[nt][r]);
                hls[nl * 64 + c] = hb;
                if (node < NN) ((unsigned short*)h1)[(size_t)node * 64 + c] = hb;
            }
        }
        __syncthreads();
        // a1s/a1d per (node, head): 64 nodes x 8 heads = 512 pairs per sub
        #pragma unroll
        for (int pp = 0; pp < 2; ++pp) {
            int p = t + pp * 256;
            int nl = p >> 3, g = p & 7;
            int node = n0 + nl;
            float ss = 0.f, dd = 0.f;
            #pragma unroll
            for (int j = 0; j < 8; ++j) {
                float hv = b2f(hls[nl * 64 + g * 8 + j]);
                ss += hv * attSl[g * 8 + j];
                dd += hv * attDl[g * 8 + j];
            }
            if (node < NN) {
                a1s[(size_t)node * NH1 + g] = ss;
                a1d[(size_t)node * NH1 + g] = dd;
            }
        }
    }
}

// ---------------- Fused layer-1 agg + layer-2 GEMM + scalar projection ----------------
// R23: R3 structure (serial dst, 8-edge x 8-lane) with the edge loop
// unrolled 4x (32-edge batch: 4 perm + 4 a1s + 4 h1-dwordx4 = 12 loads
// batch-issued) and __launch_bounds__(256,2) so the register allocator
// may hold all 12 results (R3/R4 pinned VGPR=32, throttling depth to ~6).
// Within-dst tail clamps collapse to same-address coalesced loads (cheap),
// unlike R22's cross-dst max-imbalance (51->82us regression: address-dep
// serialization + 25% wasted slots + occupancy 37%). Do not retry R22.
// R18's head-half L2 split also regressed (FETCH 90.7->104.5): do not retry.

#define HLP 72

__global__ __launch_bounds__(256, 2) void k_agg1f(
    const int* __restrict__ offs, const int* __restrict__ perm,
    const __hip_bfloat16* __restrict__ h1, const float* __restrict__ a1s,
    const float* __restrict__ a1d, const void* __restrict__ b1,
    const unsigned short* __restrict__ W2p,
    const void* __restrict__ attS2, const void* __restrict__ attD2,
    const void* __restrict__ linW,
    float2* __restrict__ g2s, float* __restrict__ a2d,
    int n, const int* __restrict__ flags) {
    int fp32 = flags[0];
    __shared__ __align__(16) unsigned short hl[16 * HLP];   // 2.25 KB helu tile (bf16 bits)
    __shared__ float attSl[64], attDl[64];
    __shared__ float sp[16 * 4], dp[16 * 4], gp[16 * 4];
    int tid = threadIdx.x;
    if (tid < 64) { attSl[tid] = loadF(attS2, tid, fp32); attDl[tid] = loadF(attD2, tid, fp32); }
    int w = tid >> 6, c = tid & 63;
    int n0 = blockIdx.x * 16;
    const unsigned short* hu = (const unsigned short*)h1;

    // ---- phase 1: aggregation, 8-edge x 8-lane scheme, unroll-4 ----
    int g = c >> 3, q = c & 7;
    float b1r[8];
    #pragma unroll
    for (int k = 0; k < 8; ++k) b1r[k] = loadF(b1, q * 8 + k, fp32);

    for (int m = 0; m < 4; ++m) {
        int d = n0 + w * 4 + m;
        if (d < n) {
            int start = offs[d], end = offs[d + 1];
            int last = end - 1;
            float adl = a1d[(size_t)d * NH1 + q];
            float accv[8];
            #pragma unroll
            for (int k = 0; k < 8; ++k) accv[k] = 0.f;
            float den = 0.f;
            for (int i = start; i < end; i += 32) {
                int j0 = i + g, j1 = i + 8 + g, j2 = i + 16 + g, j3 = i + 24 + g;
                // batch-issue all 12 loads (4 perm -> 4 a1s + 4 h1)
                int s0 = perm[min(j0, last)];
                int s1 = perm[min(j1, last)];
                int s2 = perm[min(j2, last)];
                int s3 = perm[min(j3, last)];
                float as0 = a1s[(size_t)s0 * NH1 + q];
                float as1 = a1s[(size_t)s1 * NH1 + q];
                float as2 = a1s[(size_t)s2 * NH1 + q];
                float as3 = a1s[(size_t)s3 * NH1 + q];
                u16x8 hv0 = *(const u16x8*)(hu + (size_t)s0 * 64 + q * 8);
                u16x8 hv1 = *(const u16x8*)(hu + (size_t)s1 * 64 + q * 8);
                u16x8 hv2 = *(const u16x8*)(hu + (size_t)s2 * 64 + q * 8);
                u16x8 hv3 = *(const u16x8*)(hu + (size_t)s3 * 64 + q * 8);
                float e0 = as0 + adl; e0 = fmaxf(e0, 0.2f * e0);
                float p0 = (j0 < end) ? __expf(e0) : 0.f;
                float e1 = as1 + adl; e1 = fmaxf(e1, 0.2f * e1);
                float p1 = (j1 < end) ? __expf(e1) : 0.f;
                float e2 = as2 + adl; e2 = fmaxf(e2, 0.2f * e2);
                float p2 = (j2 < end) ? __expf(e2) : 0.f;
                float e3 = as3 + adl; e3 = fmaxf(e3, 0.2f * e3);
                float p3 = (j3 < end) ? __expf(e3) : 0.f;
                den += (p0 + p1) + (p2 + p3);
                #pragma unroll
                for (int k = 0; k < 8; ++k) {
                    accv[k] = fmaf(p0, b2f(hv0[k]), accv[k]);
                    accv[k] = fmaf(p1, b2f(hv1[k]), accv[k]);
                    accv[k] = fmaf(p2, b2f(hv2[k]), accv[k]);
                    accv[k] = fmaf(p3, b2f(hv3[k]), accv[k]);
                }
            }
            // tree-reduce across the 8 edge-slots (lane bits 3,4,5)
            #pragma unroll
            for (int k = 0; k < 8; ++k) {
                accv[k] += __shfl_xor(accv[k], 8, 64);
                accv[k] += __shfl_xor(accv[k], 16, 64);
                accv[k] += __shfl_xor(accv[k], 32, 64);
            }
            den += __shfl_xor(den, 8, 64);
            den += __shfl_xor(den, 16, 64);
            den += __shfl_xor(den, 32, 64);
            float rden = 1.f / (den + 1e-16f);
            if (g == 0) {                       // lanes 0..7 write 16B each
                unsigned pk4[4];
                #pragma unroll
                for (int k = 0; k < 4; ++k) {
                    float v0 = fmaf(accv[2 * k],     rden, b1r[2 * k]);
                    float v1 = fmaf(accv[2 * k + 1], rden, b1r[2 * k + 1]);
                    v0 = (v0 > 0.f) ? v0 : expm1f(v0);       // ELU
                    v1 = (v1 > 0.f) ? v1 : expm1f(v1);
                    pk4[k] = (unsigned)f2bfu(v0) | ((unsigned)f2bfu(v1) << 16);
                }
                *(uint4*)&hl[(w * 4 + m) * HLP + q * 8] =
                    make_uint4(pk4[0], pk4[1], pk4[2], pk4[3]);
            }
        }
    }
    __syncthreads();

    // ---- phase 2: h2 tile = hl @ W2 (wave w = col-tile w); g2/a2s/a2d epilogue ----
    int quad = c >> 4, lm = c & 15;
    bf16x8 bf0 = *(const bf16x8*)(W2p + (0 * 4 + w) * 512 + c * 8);
    bf16x8 bf1 = *(const bf16x8*)(W2p + (1 * 4 + w) * 512 + c * 8);
    bf16x8 af0 = *(const bf16x8*)(hl + lm * HLP + 0 * 32 + quad * 8);
    bf16x8 af1 = *(const bf16x8*)(hl + lm * HLP + 1 * 32 + quad * 8);
    f32x4 acc2 = (f32x4){0.f, 0.f, 0.f, 0.f};
    acc2 = __builtin_amdgcn_mfma_f32_16x16x32_bf16(af0, bf0, acc2, 0, 0, 0);
    acc2 = __builtin_amdgcn_mfma_f32_16x16x32_bf16(af1, bf1, acc2, 0, 0, 0);

    int cg = w * 16 + lm;                                // global output col
    float aSc = attSl[cg], aDc = attDl[cg];
    float lWc = loadF(linW, cg, fp32);
    #pragma unroll
    for (int r = 0; r < 4; ++r) {
        int nl = quad * 4 + r;
        unsigned short hb = f2bfu(acc2[r]);              // same rounding as before
        float hv = b2f(hb);
        float pvs = hv * aSc, pvd = hv * aDc, pvg = hv * lWc;
        pvs += __shfl_xor(pvs, 1, 64); pvd += __shfl_xor(pvd, 1, 64); pvg += __shfl_xor(pvg, 1, 64);
        pvs += __shfl_xor(pvs, 2, 64); pvd += __shfl_xor(pvd, 2, 64); pvg += __shfl_xor(pvg, 2, 64);
        pvs += __shfl_xor(pvs, 4, 64); pvd += __shfl_xor(pvd, 4, 64); pvg += __shfl_xor(pvg, 4, 64);
        pvs += __shfl_xor(pvs, 8, 64); pvd += __shfl_xor(pvd, 8, 64); pvg += __shfl_xor(pvg, 8, 64);
        if (lm == 0) { sp[nl * 4 + w] = pvs; dp[nl * 4 + w] = pvd; gp[nl * 4 + w] = pvg; }
    }
    __syncthreads();
    if (tid < 16) {
        int node = n0 + tid;
        if (node < n) {
            float ss = sp[tid * 4 + 0] + sp[tid * 4 + 1] + sp[tid * 4 + 2] + sp[tid * 4 + 3];
            float dd = dp[tid * 4 + 0] + dp[tid * 4 + 1] + dp[tid * 4 + 2] + dp[tid * 4 + 3];
            float gg = gp[tid * 4 + 0] + gp[tid * 4 + 1] + gp[tid * 4 + 2] + gp[tid * 4 + 3];
            g2s[node] = make_float2(ss, gg);
            a2d[node] = dd;
        }
    }
}

// ---------------- Layer 2 aggregation, scalar form ----------------
// out[d] = sum_e p_e * g2[s_e] / den + (b2·linW + linb). Per edge: one perm
// read + one 8B gather + ~6 VALU; lanes work disjoint edges.

__global__ __launch_bounds__(256) void k_agg2(
    const int* __restrict__ offs, const int* __restrict__ perm,
    const float2* __restrict__ g2s, const float* __restrict__ a2d,
    const void* __restrict__ b2, const void* __restrict__ linW,
    const void* __restrict__ linb,
    void* __restrict__ out, int n, const int* __restrict__ flags) {
    int fp32 = flags[0];
    int w = threadIdx.x >> 6, c = threadIdx.x & 63;
    int d = blockIdx.x * 4 + w;
    if (d >= n) return;
    int start = offs[d], end = offs[d + 1];
    float ad = a2d[d];
    float acc = 0.f, den = 0.f;
    for (int i = start + c; i < end; i += 64) {
        int s = perm[i];
        float2 ag = g2s[s];
        float e = ag.x + ad;
        e = fmaxf(e, 0.2f * e);                      // leaky_relu(0.2)
        float p = __expf(e);
        acc = fmaf(p, ag.y, acc);
        den += p;
    }
    float cst = loadF(b2, c, fp32) * loadF(linW, c, fp32);   // b2·linW partial
    #pragma unroll
    for (int off = 1; off < 64; off <<= 1) {
        acc += __shfl_xor(acc, off, 64);
        den += __shfl_xor(den, off, 64);
        cst += __shfl_xor(cst, off, 64);
    }
    if (c == 0) {
        float r = acc / (den + 1e-16f) + cst + loadF(linb, 0, fp32);
        if (fp32) ((float*)out)[d] = r;
        else      ((__hip_bfloat16*)out)[d] = __float2bfloat16(r);
    }
}

// ---------------- host launcher ----------------

static inline char* carve(char*& p, size_t bytes) {
    char* r = p;
    p += (bytes + 255) & ~size_t(255);
    return r;
}

extern "C" void kernel_launch(void* const* d_in, const int* in_sizes, int n_in,
                              void* d_out, int out_size, void* d_ws, size_t ws_size,
                              hipStream_t stream) {
    const void* x     = d_in[0];
    const void* ei    = d_in[1];
    const void* W1    = d_in[2];
    const void* attS1 = d_in[3];
    const void* attD1 = d_in[4];
    const void* b1    = d_in[5];
    const void* W2    = d_in[6];
    const void* attS2 = d_in[7];
    const void* attD2 = d_in[8];
    const void* b2    = d_in[9];
    const void* linW  = d_in[10];
    const void* linb  = d_in[11];

    int E    = in_sizes[1] / 2;
    int Etot = E + NN;

    // workspace layout (~25 MB)
    char* p = (char*)d_ws;
    int*   flags = (int*)carve(p, 256);
    int*   bcnt  = (int*)carve(p, (size_t)NB * 4);
    unsigned short* W1p = (unsigned short*)carve(p, 8192 * 2);
    unsigned short* W2p = (unsigned short*)carve(p, 4096 * 2);
    int*   offs  = (int*)carve(p, (size_t)(NN + 1) * 4);       // 200 KB
    int*   perm  = (int*)carve(p, (size_t)Etot * 4);           // 6.6 MB
    // binned has its own region (k_mid overlaps csr reads with mgemm writes)
    unsigned* binned = (unsigned*)carve(p, (size_t)NB * BCAP * 4);  // 7.43 MB
    float*    a1s    = (float*)carve(p, (size_t)NN * NH1 * 4);      // 1.6 MB
    float*    a1d    = (float*)carve(p, (size_t)NN * NH1 * 4);      // 1.6 MB
    __hip_bfloat16* h1 = (__hip_bfloat16*)carve(p, (size_t)NN * F1 * 2);  // 6.4 MB
    float2* g2s = (float2*)carve(p, (size_t)NN * 8);           // 400 KB (a2s, g2)
    float*  a2d = (float*)carve(p, (size_t)NN * 4);            // 200 KB

    hipMemsetAsync(bcnt, 0, (size_t)NB * 4, stream);

    int nbin = (Etot + 8191) / 8192;
    k_front<<<PREB + nbin, 1024, 0, stream>>>(x, ei, E, Etot, flags,
                                              W1, W2, W1p, W2p, bcnt, binned);
    k_mid<<<NB + MG1B, 1024, 0, stream>>>(bcnt, binned, offs, perm,
                                          x, W1p, attS1, attD1, h1, a1s, a1d, flags);
    k_agg1f<<<(NN + 15) / 16, 256, 0, stream>>>(offs, perm, h1, a1s, a1d, b1,
                                                W2p, attS2, attD2, linW, g2s, a2d, NN, flags);
    k_agg2<<<(NN + 3) / 4, 256, 0, stream>>>(offs, perm, g2s, a2d, b2, linW, linb, d_out, NN, flags);
}

// Round 8
// 193.530 us; speedup vs baseline: 1.1196x; 1.0554x over previous
//
#include <hip/hip_runtime.h>
#include <hip/hip_bf16.h>
#include <math.h>

#define NN     50000
#define FIN    128
#define F1     64      // H1*C1 = layer-1 output features
#define NH1    8
#define F2     64      // layer-2 output features

#define BSH    256                         // nodes per dst bucket (CSR build)
#define NB     ((NN + BSH - 1) / BSH)      // 196 buckets
#define BCAP   9472                        // per-bucket edge cap (mean 8448, +11 sigma)
#define PREB   13                          // swizzle blocks in k_front
#define MG1B   ((NN + 255) / 256)          // 196 mgemm1 super-blocks in k_mid

typedef __bf16 bf16x8 __attribute__((ext_vector_type(8)));
typedef float  f32x4  __attribute__((ext_vector_type(4)));
typedef unsigned short u16x8 __attribute__((ext_vector_type(8)));

// ---------------- runtime dtype helpers ----------------
// flags[0] = 1 if float tensors are fp32 (else bf16)
// flags[1] = 1 if edge_index is int64 (else int32)

__device__ __forceinline__ float loadF(const void* p, long long i, int fp32) {
    if (fp32) return ((const float*)p)[i];
    return __bfloat162float(((const __hip_bfloat16*)p)[i]);
}
__device__ __forceinline__ int loadI_nt(const void* p, long long i, int i64) {
    if (i64) return (int)__builtin_nontemporal_load(&((const long long*)p)[i]);
    return __builtin_nontemporal_load(&((const int*)p)[i]);
}
__device__ __forceinline__ unsigned short f2bfu(float f) {   // RNE f32->bf16 bits
    unsigned u = __float_as_uint(f);
    return (unsigned short)((u + 0x7FFFu + ((u >> 16) & 1u)) >> 16);
}
__device__ __forceinline__ float b2f(unsigned short u) {
    return __uint_as_float(((unsigned)u) << 16);
}

// ---------------- k_front: [sniff + W-swizzle] | [edge binning] (R15) ----------------

__global__ __launch_bounds__(1024) void k_front(
    const void* __restrict__ x, const void* __restrict__ ei, int E, int Etot,
    int* __restrict__ flags,
    const void* __restrict__ W1, const void* __restrict__ W2,
    unsigned short* __restrict__ W1p, unsigned short* __restrict__ W2p,
    int* __restrict__ bcnt, unsigned* __restrict__ binned) {
    __shared__ int s_a, s_b;
    __shared__ int hist[NB], gbase[NB];
    int tid = threadIdx.x;
    if (blockIdx.x < PREB) {
        if (tid == 0) { s_a = 0; s_b = 0; }
        __syncthreads();
        const unsigned short* u = (const unsigned short*)x;
        int cnt = 0;
        for (int i = tid; i < 8192; i += 1024) {
            unsigned short v = u[i];
            if ((v & 0x7F80) == 0x7F80) cnt++;     // bf16 Inf/NaN pattern
        }
        if (cnt) atomicAdd(&s_a, cnt);
        const unsigned* e32 = (const unsigned*)ei;
        int nz = 0;
        for (int i = tid; i < 2048; i += 1024) {
            if (e32[2 * i + 1] != 0u) nz++;        // high words if int64
        }
        if (nz) atomicAdd(&s_b, nz);
        __syncthreads();
        int fp32 = (s_a > 2) ? 1 : 0;
        if (tid == 0 && blockIdx.x == 0) {
            flags[0] = fp32;
            flags[1] = (s_b == 0) ? 1 : 0;
        }
        int gt = blockIdx.x * 1024 + tid, gs = PREB * 1024;
        for (int i = gt; i < (FIN / 32) * 4 * 512; i += gs) {   // 8192
            int j = i & 7, l = (i >> 3) & 63, f = i >> 9;
            int kb = f >> 2, nt = f & 3;
            int k = kb * 32 + (l >> 4) * 8 + j, n = nt * 16 + (l & 15);
            W1p[i] = f2bfu(loadF(W1, k * 64 + n, fp32));
        }
        for (int i = gt; i < (F1 / 32) * 4 * 512; i += gs) {    // 4096
            int j = i & 7, l = (i >> 3) & 63, f = i >> 9;
            int kb = f >> 2, nt = f & 3;
            int k = kb * 32 + (l >> 4) * 8 + j, n = nt * 16 + (l & 15);
            W2p[i] = f2bfu(loadF(W2, k * 64 + n, fp32));
        }
    } else {
        // ---- bin role (own int-width sniff) ----
        if (tid == 0) s_b = 0;
        for (int i = tid; i < NB; i += 1024) hist[i] = 0;
        __syncthreads();
        const unsigned* e32 = (const unsigned*)ei;
        int nz = 0;
        for (int i = tid; i < 2048; i += 1024) {
            if (e32[2 * i + 1] != 0u) nz++;
        }
        if (nz) atomicAdd(&s_b, nz);
        __syncthreads();
        int i64 = (s_b == 0) ? 1 : 0;
        long long base = (long long)(blockIdx.x - PREB) * 8192;
        unsigned pk[8]; short bb[8];
        #pragma unroll
        for (int u = 0; u < 8; ++u) {
            long long j = base + u * 1024 + tid;
            int s = -1, d = -1;
            if (j < Etot) {
                if (j < E) { s = loadI_nt(ei, j, i64); d = loadI_nt(ei, (long long)E + j, i64); }
                else       { s = d = (int)(j - E); }
            }
            if ((unsigned)s < NN && (unsigned)d < NN) {
                bb[u] = (short)(d >> 8);
                pk[u] = ((unsigned)s << 8) | (unsigned)(d & 255);
                atomicAdd(&hist[bb[u]], 1);
            } else bb[u] = -1;
        }
        __syncthreads();
        for (int i = tid; i < NB; i += 1024) {
            int h = hist[i];
            gbase[i] = h ? atomicAdd(&bcnt[i], h) : 0;
            hist[i] = 0;                             // reuse as local cursor
        }
        __syncthreads();
        #pragma unroll
        for (int u = 0; u < 8; ++u) {
            if (bb[u] >= 0) {
                int pos = gbase[bb[u]] + atomicAdd(&hist[bb[u]], 1);
                if (pos < BCAP) binned[(size_t)bb[u] * BCAP + pos] = pk[u];
            }
        }
    }
}

// ---------------- k_mid: [CSR counting sort] | [layer-1 MFMA GEMM] (R15) ----------------

__global__ __launch_bounds__(1024) void k_mid(
    const int* __restrict__ bcnt, const unsigned* __restrict__ binned,
    int* __restrict__ offs, int* __restrict__ perm,
    const void* __restrict__ x, const unsigned short* __restrict__ W1p,
    const void* __restrict__ attS, const void* __restrict__ attD,
    __hip_bfloat16* __restrict__ h1, float* __restrict__ a1s,
    float* __restrict__ a1d, const int* __restrict__ flags) {
    __shared__ __align__(16) char smem[33280];     // max(csr 3KB, mgemm 33KB)
    int tid = threadIdx.x;
    if (blockIdx.x < NB) {
        int* hist = (int*)smem;
        int* cur  = (int*)(smem + 1024);
        int* sd   = (int*)(smem + 2048);
        int bk = blockIdx.x;
        int n0 = bk * BSH;
        if (tid < 256) sd[tid] = (tid < NB) ? min(bcnt[tid], BCAP) : 0;
        __syncthreads();
        for (int off = 1; off < BSH; off <<= 1) {
            int t = 0;
            if (tid < 256 && tid >= off) t = sd[tid - off];
            __syncthreads();
            if (tid < 256) sd[tid] += t;
            __syncthreads();
        }
        int gb = (bk > 0) ? sd[bk - 1] : 0;
        if (bk == 0 && tid == 0) offs[NN] = sd[NB - 1];
        __syncthreads();
        int cnt = bcnt[bk]; if (cnt > BCAP) cnt = BCAP;
        const unsigned* bp = binned + (size_t)bk * BCAP;
        if (tid < 256) hist[tid] = 0;
        __syncthreads();
        for (int i = tid; i < cnt; i += 1024)
            atomicAdd(&hist[bp[i] & 255], 1);
        __syncthreads();
        int myh = (tid < 256) ? hist[tid] : 0;
        if (tid < 256) sd[tid] = myh;
        __syncthreads();
        for (int off = 1; off < BSH; off <<= 1) {
            int t = 0;
            if (tid < 256 && tid >= off) t = sd[tid - off];
            __syncthreads();
            if (tid < 256) sd[tid] += t;
            __syncthreads();
        }
        if (tid < 256) {
            int excl = sd[tid] - myh;
            cur[tid] = gb + excl;
            if (n0 + tid < NN) offs[n0 + tid] = gb + excl;
        }
        __syncthreads();
        for (int i = tid; i < cnt; i += 1024) {
            unsigned pk = bp[i];
            int pos = atomicAdd(&cur[pk & 255], 1);
            perm[pos] = (int)(pk >> 8);
        }
    } else {
        // ---- mgemm1 role: 4 sub-tiles of 64 nodes ----
        int fp32 = flags[0];
        unsigned short* hl = (unsigned short*)smem;          // 4 x 4096 ushort
        float* attSl = (float*)(smem + 32768);
        float* attDl = (float*)(smem + 32768 + 256);
        if (tid < 64) { attSl[tid] = loadF(attS, tid, fp32); attDl[tid] = loadF(attD, tid, fp32); }
        int sub = tid >> 8, t = tid & 255;
        int w = t >> 6, l = t & 63;
        int quad = l >> 4, lm = l & 15;
        int n0 = (blockIdx.x - NB) * 256 + sub * 64;
        unsigned short* hls = hl + sub * 4096;

        bf16x8 bfr[16];
        #pragma unroll
        for (int f = 0; f < 16; ++f)
            bfr[f] = *(const bf16x8*)(W1p + f * 512 + l * 8);

        int nodeA = n0 + w * 16 + lm;
        long long rowA = (nodeA < NN) ? nodeA : 0;     // clamp; garbage unused
        f32x4 acc[4];
        #pragma unroll
        for (int nt = 0; nt < 4; ++nt) acc[nt] = (f32x4){0.f, 0.f, 0.f, 0.f};

        #pragma unroll
        for (int kb = 0; kb < 4; ++kb) {
            bf16x8 af;
            if (!fp32) {
                af = *(const bf16x8*)((const unsigned short*)x + rowA * FIN + kb * 32 + quad * 8);
            } else {
                const float* xf = (const float*)x + rowA * FIN + kb * 32 + quad * 8;
                union { unsigned short s[8]; bf16x8 v; } tmp;
                #pragma unroll
                for (int j = 0; j < 8; ++j) tmp.s[j] = f2bfu(xf[j]);
                af = tmp.v;
            }
            #pragma unroll
            for (int nt = 0; nt < 4; ++nt)
                acc[nt] = __builtin_amdgcn_mfma_f32_16x16x32_bf16(af, bfr[kb * 4 + nt], acc[nt], 0, 0, 0);
        }

        #pragma unroll
        for (int nt = 0; nt < 4; ++nt) {
            #pragma unroll
            for (int r = 0; r < 4; ++r) {
                int nl = w * 16 + quad * 4 + r;
                int node = n0 + nl;
                int c = nt * 16 + lm;
                unsigned short hb = f2bfu(acc[nt][r]);
                hls[nl * 64 + c] = hb;
                if (node < NN) ((unsigned short*)h1)[(size_t)node * 64 + c] = hb;
            }
        }
        __syncthreads();
        // a1s/a1d per (node, head): 64 nodes x 8 heads = 512 pairs per sub
        #pragma unroll
        for (int pp = 0; pp < 2; ++pp) {
            int p = t + pp * 256;
            int nl = p >> 3, g = p & 7;
            int node = n0 + nl;
            float ss = 0.f, dd = 0.f;
            #pragma unroll
            for (int j = 0; j < 8; ++j) {
                float hv = b2f(hls[nl * 64 + g * 8 + j]);
                ss += hv * attSl[g * 8 + j];
                dd += hv * attDl[g * 8 + j];
            }
            if (node < NN) {
                a1s[(size_t)node * NH1 + g] = ss;
                a1d[(size_t)node * NH1 + g] = dd;
            }
        }
    }
}

// ---------------- Fused layer-1 agg + layer-2 GEMM + scalar projection ----------------
// R24 = R3/R19 verbatim (best measured: 51.5 us): 8-edge x 8-lane mapping,
// edge loop unrolled 2x with both batches' loads issued before consumption,
// plain __launch_bounds__(256) (VGPR 32, ~60% occupancy).
// CLOSED LINES for k_agg1f (all measured worse or null):
//   R4  sw-pipeline: compiler folds it (null).  R18 L2 half-split: +15% FETCH.
//   R22 4-dst interleave: 82us (addr-dep serial + imbalance + occupancy).
//   R23 unroll-4 @(256,2): 57.4us (occupancy 42% outweighs depth 12).
// k_agg1f sits at the L2-capacity FETCH floor (~90MB) at ~1.8 TB/s service.

#define HLP 72

__global__ __launch_bounds__(256) void k_agg1f(
    const int* __restrict__ offs, const int* __restrict__ perm,
    const __hip_bfloat16* __restrict__ h1, const float* __restrict__ a1s,
    const float* __restrict__ a1d, const void* __restrict__ b1,
    const unsigned short* __restrict__ W2p,
    const void* __restrict__ attS2, const void* __restrict__ attD2,
    const void* __restrict__ linW,
    float2* __restrict__ g2s, float* __restrict__ a2d,
    int n, const int* __restrict__ flags) {
    int fp32 = flags[0];
    __shared__ __align__(16) unsigned short hl[16 * HLP];   // 2.25 KB helu tile (bf16 bits)
    __shared__ float attSl[64], attDl[64];
    __shared__ float sp[16 * 4], dp[16 * 4], gp[16 * 4];
    int tid = threadIdx.x;
    if (tid < 64) { attSl[tid] = loadF(attS2, tid, fp32); attDl[tid] = loadF(attD2, tid, fp32); }
    int w = tid >> 6, c = tid & 63;
    int n0 = blockIdx.x * 16;
    const unsigned short* hu = (const unsigned short*)h1;

    // ---- phase 1: aggregation, 8-edge x 8-lane scheme, unroll-2 ----
    int g = c >> 3, q = c & 7;
    float b1r[8];
    #pragma unroll
    for (int k = 0; k < 8; ++k) b1r[k] = loadF(b1, q * 8 + k, fp32);

    for (int m = 0; m < 4; ++m) {
        int d = n0 + w * 4 + m;
        if (d < n) {
            int start = offs[d], end = offs[d + 1];
            float adl = a1d[(size_t)d * NH1 + q];
            float accv[8];
            #pragma unroll
            for (int k = 0; k < 8; ++k) accv[k] = 0.f;
            float den = 0.f;
            for (int i = start; i < end; i += 16) {
                int j0 = i + g, j1 = i + 8 + g;
                int jc0 = (j0 < end) ? j0 : (end - 1);
                int jc1 = (j1 < end) ? j1 : (end - 1);
                // batch-issue all loads for both 8-edge groups
                int sj0 = perm[jc0];
                int sj1 = perm[jc1];
                float as0 = a1s[(size_t)sj0 * NH1 + q];
                float as1 = a1s[(size_t)sj1 * NH1 + q];
                u16x8 hv0 = *(const u16x8*)(hu + (size_t)sj0 * 64 + q * 8);
                u16x8 hv1 = *(const u16x8*)(hu + (size_t)sj1 * 64 + q * 8);
                float e0 = as0 + adl;
                e0 = fmaxf(e0, 0.2f * e0);                   // leaky_relu(0.2)
                float p0 = (j0 < end) ? __expf(e0) : 0.f;
                float e1 = as1 + adl;
                e1 = fmaxf(e1, 0.2f * e1);
                float p1 = (j1 < end) ? __expf(e1) : 0.f;
                den += p0 + p1;
                #pragma unroll
                for (int k = 0; k < 8; ++k) {
                    accv[k] = fmaf(p0, b2f(hv0[k]), accv[k]);
                    accv[k] = fmaf(p1, b2f(hv1[k]), accv[k]);
                }
            }
            // tree-reduce across the 8 edge-slots (lane bits 3,4,5)
            #pragma unroll
            for (int k = 0; k < 8; ++k) {
                accv[k] += __shfl_xor(accv[k], 8, 64);
                accv[k] += __shfl_xor(accv[k], 16, 64);
                accv[k] += __shfl_xor(accv[k], 32, 64);
            }
            den += __shfl_xor(den, 8, 64);
            den += __shfl_xor(den, 16, 64);
            den += __shfl_xor(den, 32, 64);
            float rden = 1.f / (den + 1e-16f);
            if (g == 0) {                       // lanes 0..7 write 16B each
                unsigned pk4[4];
                #pragma unroll
                for (int k = 0; k < 4; ++k) {
                    float v0 = fmaf(accv[2 * k],     rden, b1r[2 * k]);
                    float v1 = fmaf(accv[2 * k + 1], rden, b1r[2 * k + 1]);
                    v0 = (v0 > 0.f) ? v0 : expm1f(v0);       // ELU
                    v1 = (v1 > 0.f) ? v1 : expm1f(v1);
                    pk4[k] = (unsigned)f2bfu(v0) | ((unsigned)f2bfu(v1) << 16);
                }
                *(uint4*)&hl[(w * 4 + m) * HLP + q * 8] =
                    make_uint4(pk4[0], pk4[1], pk4[2], pk4[3]);
            }
        }
    }
    __syncthreads();

    // ---- phase 2: h2 tile = hl @ W2 (wave w = col-tile w); g2/a2s/a2d epilogue ----
    int quad = c >> 4, lm = c & 15;
    bf16x8 bf0 = *(const bf16x8*)(W2p + (0 * 4 + w) * 512 + c * 8);
    bf16x8 bf1 = *(const bf16x8*)(W2p + (1 * 4 + w) * 512 + c * 8);
    bf16x8 af0 = *(const bf16x8*)(hl + lm * HLP + 0 * 32 + quad * 8);
    bf16x8 af1 = *(const bf16x8*)(hl + lm * HLP + 1 * 32 + quad * 8);
    f32x4 acc2 = (f32x4){0.f, 0.f, 0.f, 0.f};
    acc2 = __builtin_amdgcn_mfma_f32_16x16x32_bf16(af0, bf0, acc2, 0, 0, 0);
    acc2 = __builtin_amdgcn_mfma_f32_16x16x32_bf16(af1, bf1, acc2, 0, 0, 0);

    int cg = w * 16 + lm;                                // global output col
    float aSc = attSl[cg], aDc = attDl[cg];
    float lWc = loadF(linW, cg, fp32);
    #pragma unroll
    for (int r = 0; r < 4; ++r) {
        int nl = quad * 4 + r;
        unsigned short hb = f2bfu(acc2[r]);              // same rounding as before
        float hv = b2f(hb);
        float pvs = hv * aSc, pvd = hv * aDc, pvg = hv * lWc;
        pvs += __shfl_xor(pvs, 1, 64); pvd += __shfl_xor(pvd, 1, 64); pvg += __shfl_xor(pvg, 1, 64);
        pvs += __shfl_xor(pvs, 2, 64); pvd += __shfl_xor(pvd, 2, 64); pvg += __shfl_xor(pvg, 2, 64);
        pvs += __shfl_xor(pvs, 4, 64); pvd += __shfl_xor(pvd, 4, 64); pvg += __shfl_xor(pvg, 4, 64);
        pvs += __shfl_xor(pvs, 8, 64); pvd += __shfl_xor(pvd, 8, 64); pvg += __shfl_xor(pvg, 8, 64);
        if (lm == 0) { sp[nl * 4 + w] = pvs; dp[nl * 4 + w] = pvd; gp[nl * 4 + w] = pvg; }
    }
    __syncthreads();
    if (tid < 16) {
        int node = n0 + tid;
        if (node < n) {
            float ss = sp[tid * 4 + 0] + sp[tid * 4 + 1] + sp[tid * 4 + 2] + sp[tid * 4 + 3];
            float dd = dp[tid * 4 + 0] + dp[tid * 4 + 1] + dp[tid * 4 + 2] + dp[tid * 4 + 3];
            float gg = gp[tid * 4 + 0] + gp[tid * 4 + 1] + gp[tid * 4 + 2] + gp[tid * 4 + 3];
            g2s[node] = make_float2(ss, gg);
            a2d[node] = dd;
        }
    }
}

// ---------------- Layer 2 aggregation, 8-lane groups (R24) ----------------
// Mean degree ~33: the old 64-lane-per-dst loop ran ONE trip with half the
// wave idle, then paid 3 values x 6 shuffles = 18 cross-lane ops per dst.
// Now: 8 lanes per dst (32 dsts per 256-thread block), uniform cst=b2·linW
// hoisted to one per-wave 6-shuffle reduce, per-dst finish is 2 values x
// 3 shuffles. Lane-slot efficiency ~52%->~80%; reduction ops per dst ~4x
// fewer. Memory pattern unchanged (g2s = 400KB, L2-resident).

__global__ __launch_bounds__(256) void k_agg2(
    const int* __restrict__ offs, const int* __restrict__ perm,
    const float2* __restrict__ g2s, const float* __restrict__ a2d,
    const void* __restrict__ b2, const void* __restrict__ linW,
    const void* __restrict__ linb,
    void* __restrict__ out, int n, const int* __restrict__ flags) {
    int fp32 = flags[0];
    int tid = threadIdx.x;
    int lane = tid & 63, wv = tid >> 6;
    int grp = lane >> 3, l8 = lane & 7;       // 8 groups of 8 lanes per wave
    // cst = dot(b2, linW) (uniform over dsts): one per-wave full reduce
    float cst = loadF(b2, lane, fp32) * loadF(linW, lane, fp32);
    #pragma unroll
    for (int off = 1; off < 64; off <<= 1) cst += __shfl_xor(cst, off, 64);
    cst += loadF(linb, 0, fp32);

    int d = blockIdx.x * 32 + wv * 8 + grp;
    if (d >= n) return;
    int start = offs[d], end = offs[d + 1];
    float ad = a2d[d];
    float acc = 0.f, den = 0.f;
    for (int i = start + l8; i < end; i += 8) {
        int s = perm[i];
        float2 ag = g2s[s];
        float e = ag.x + ad;
        e = fmaxf(e, 0.2f * e);                      // leaky_relu(0.2)
        float p = __expf(e);
        acc = fmaf(p, ag.y, acc);
        den += p;
    }
    // reduce within the 8-lane group (lane bits 0..2)
    acc += __shfl_xor(acc, 1, 64); den += __shfl_xor(den, 1, 64);
    acc += __shfl_xor(acc, 2, 64); den += __shfl_xor(den, 2, 64);
    acc += __shfl_xor(acc, 4, 64); den += __shfl_xor(den, 4, 64);
    if (l8 == 0) {
        float r = acc / (den + 1e-16f) + cst;
        if (fp32) ((float*)out)[d] = r;
        else      ((__hip_bfloat16*)out)[d] = __float2bfloat16(r);
    }
}

// ---------------- host launcher ----------------

static inline char* carve(char*& p, size_t bytes) {
    char* r = p;
    p += (bytes + 255) & ~size_t(255);
    return r;
}

extern "C" void kernel_launch(void* const* d_in, const int* in_sizes, int n_in,
                              void* d_out, int out_size, void* d_ws, size_t ws_size,
                              hipStream_t stream) {
    const void* x     = d_in[0];
    const void* ei    = d_in[1];
    const void* W1    = d_in[2];
    const void* attS1 = d_in[3];
    const void* attD1 = d_in[4];
    const void* b1    = d_in[5];
    const void* W2    = d_in[6];
    const void* attS2 = d_in[7];
    const void* attD2 = d_in[8];
    const void* b2    = d_in[9];
    const void* linW  = d_in[10];
    const void* linb  = d_in[11];

    int E    = in_sizes[1] / 2;
    int Etot = E + NN;

    // workspace layout (~25 MB)
    char* p = (char*)d_ws;
    int*   flags = (int*)carve(p, 256);
    int*   bcnt  = (int*)carve(p, (size_t)NB * 4);
    unsigned short* W1p = (unsigned short*)carve(p, 8192 * 2);
    unsigned short* W2p = (unsigned short*)carve(p, 4096 * 2);
    int*   offs  = (int*)carve(p, (size_t)(NN + 1) * 4);       // 200 KB
    int*   perm  = (int*)carve(p, (size_t)Etot * 4);           // 6.6 MB
    // binned has its own region (k_mid overlaps csr reads with mgemm writes)
    unsigned* binned = (unsigned*)carve(p, (size_t)NB * BCAP * 4);  // 7.43 MB
    float*    a1s    = (float*)carve(p, (size_t)NN * NH1 * 4);      // 1.6 MB
    float*    a1d    = (float*)carve(p, (size_t)NN * NH1 * 4);      // 1.6 MB
    __hip_bfloat16* h1 = (__hip_bfloat16*)carve(p, (size_t)NN * F1 * 2);  // 6.4 MB
    float2* g2s = (float2*)carve(p, (size_t)NN * 8);           // 400 KB (a2s, g2)
    float*  a2d = (float*)carve(p, (size_t)NN * 4);            // 200 KB

    hipMemsetAsync(bcnt, 0, (size_t)NB * 4, stream);

    int nbin = (Etot + 8191) / 8192;
    k_front<<<PREB + nbin, 1024, 0, stream>>>(x, ei, E, Etot, flags,
                                              W1, W2, W1p, W2p, bcnt, binned);
    k_mid<<<NB + MG1B, 1024, 0, stream>>>(bcnt, binned, offs, perm,
                                          x, W1p, attS1, attD1, h1, a1s, a1d, flags);
    k_agg1f<<<(NN + 15) / 16, 256, 0, stream>>>(offs, perm, h1, a1s, a1d, b1,
                                                W2p, attS2, attD2, linW, g2s, a2d, NN, flags);
    k_agg2<<<(NN + 31) / 32, 256, 0, stream>>>(offs, perm, g2s, a2d, b2, linW, linb, d_out, NN, flags);
}

// Round 9
// 191.497 us; speedup vs baseline: 1.1315x; 1.0106x over previous
//
#include <hip/hip_runtime.h>
#include <hip/hip_bf16.h>
#include <math.h>

#define NN     50000
#define FIN    128
#define F1     64      // H1*C1 = layer-1 output features
#define NH1    8
#define F2     64      // layer-2 output features

#define BSH    256                         // nodes per dst bucket (CSR build)
#define NB     ((NN + BSH - 1) / BSH)      // 196 buckets
#define BCAP   9472                        // per-bucket edge cap (mean 8448, +11 sigma)
#define PREB   13                          // swizzle blocks in k_front
#define MG1B   ((NN + 255) / 256)          // 196 mgemm1 super-blocks in k_mid

typedef __bf16 bf16x8 __attribute__((ext_vector_type(8)));
typedef float  f32x4  __attribute__((ext_vector_type(4)));
typedef unsigned short u16x8 __attribute__((ext_vector_type(8)));

// ---------------- runtime dtype helpers ----------------
// flags[0] = 1 if float tensors are fp32 (else bf16)
// flags[1] = 1 if edge_index is int64 (else int32)

__device__ __forceinline__ float loadF(const void* p, long long i, int fp32) {
    if (fp32) return ((const float*)p)[i];
    return __bfloat162float(((const __hip_bfloat16*)p)[i]);
}
__device__ __forceinline__ int loadI_nt(const void* p, long long i, int i64) {
    if (i64) return (int)__builtin_nontemporal_load(&((const long long*)p)[i]);
    return __builtin_nontemporal_load(&((const int*)p)[i]);
}
__device__ __forceinline__ unsigned short f2bfu(float f) {   // RNE f32->bf16 bits
    unsigned u = __float_as_uint(f);
    return (unsigned short)((u + 0x7FFFu + ((u >> 16) & 1u)) >> 16);
}
__device__ __forceinline__ float b2f(unsigned short u) {
    return __uint_as_float(((unsigned)u) << 16);
}

// ---------------- k_front: [sniff + W-swizzle] | [edge binning] (R15) ----------------

__global__ __launch_bounds__(1024) void k_front(
    const void* __restrict__ x, const void* __restrict__ ei, int E, int Etot,
    int* __restrict__ flags,
    const void* __restrict__ W1, const void* __restrict__ W2,
    unsigned short* __restrict__ W1p, unsigned short* __restrict__ W2p,
    int* __restrict__ bcnt, unsigned* __restrict__ binned) {
    __shared__ int s_a, s_b;
    __shared__ int hist[NB], gbase[NB];
    int tid = threadIdx.x;
    if (blockIdx.x < PREB) {
        if (tid == 0) { s_a = 0; s_b = 0; }
        __syncthreads();
        const unsigned short* u = (const unsigned short*)x;
        int cnt = 0;
        for (int i = tid; i < 8192; i += 1024) {
            unsigned short v = u[i];
            if ((v & 0x7F80) == 0x7F80) cnt++;     // bf16 Inf/NaN pattern
        }
        if (cnt) atomicAdd(&s_a, cnt);
        const unsigned* e32 = (const unsigned*)ei;
        int nz = 0;
        for (int i = tid; i < 2048; i += 1024) {
            if (e32[2 * i + 1] != 0u) nz++;        // high words if int64
        }
        if (nz) atomicAdd(&s_b, nz);
        __syncthreads();
        int fp32 = (s_a > 2) ? 1 : 0;
        if (tid == 0 && blockIdx.x == 0) {
            flags[0] = fp32;
            flags[1] = (s_b == 0) ? 1 : 0;
        }
        int gt = blockIdx.x * 1024 + tid, gs = PREB * 1024;
        for (int i = gt; i < (FIN / 32) * 4 * 512; i += gs) {   // 8192
            int j = i & 7, l = (i >> 3) & 63, f = i >> 9;
            int kb = f >> 2, nt = f & 3;
            int k = kb * 32 + (l >> 4) * 8 + j, n = nt * 16 + (l & 15);
            W1p[i] = f2bfu(loadF(W1, k * 64 + n, fp32));
        }
        for (int i = gt; i < (F1 / 32) * 4 * 512; i += gs) {    // 4096
            int j = i & 7, l = (i >> 3) & 63, f = i >> 9;
            int kb = f >> 2, nt = f & 3;
            int k = kb * 32 + (l >> 4) * 8 + j, n = nt * 16 + (l & 15);
            W2p[i] = f2bfu(loadF(W2, k * 64 + n, fp32));
        }
    } else {
        // ---- bin role (own int-width sniff) ----
        if (tid == 0) s_b = 0;
        for (int i = tid; i < NB; i += 1024) hist[i] = 0;
        __syncthreads();
        const unsigned* e32 = (const unsigned*)ei;
        int nz = 0;
        for (int i = tid; i < 2048; i += 1024) {
            if (e32[2 * i + 1] != 0u) nz++;
        }
        if (nz) atomicAdd(&s_b, nz);
        __syncthreads();
        int i64 = (s_b == 0) ? 1 : 0;
        long long base = (long long)(blockIdx.x - PREB) * 8192;
        unsigned pk[8]; short bb[8];
        #pragma unroll
        for (int u = 0; u < 8; ++u) {
            long long j = base + u * 1024 + tid;
            int s = -1, d = -1;
            if (j < Etot) {
                if (j < E) { s = loadI_nt(ei, j, i64); d = loadI_nt(ei, (long long)E + j, i64); }
                else       { s = d = (int)(j - E); }
            }
            if ((unsigned)s < NN && (unsigned)d < NN) {
                bb[u] = (short)(d >> 8);
                pk[u] = ((unsigned)s << 8) | (unsigned)(d & 255);
                atomicAdd(&hist[bb[u]], 1);
            } else bb[u] = -1;
        }
        __syncthreads();
        for (int i = tid; i < NB; i += 1024) {
            int h = hist[i];
            gbase[i] = h ? atomicAdd(&bcnt[i], h) : 0;
            hist[i] = 0;                             // reuse as local cursor
        }
        __syncthreads();
        #pragma unroll
        for (int u = 0; u < 8; ++u) {
            if (bb[u] >= 0) {
                int pos = gbase[bb[u]] + atomicAdd(&hist[bb[u]], 1);
                if (pos < BCAP) binned[(size_t)bb[u] * BCAP + pos] = pk[u];
            }
        }
    }
}

// ---------------- k_mid: [CSR counting sort] | [layer-1 MFMA GEMM] (R15) ----------------

__global__ __launch_bounds__(1024) void k_mid(
    const int* __restrict__ bcnt, const unsigned* __restrict__ binned,
    int* __restrict__ offs, int* __restrict__ perm,
    const void* __restrict__ x, const unsigned short* __restrict__ W1p,
    const void* __restrict__ attS, const void* __restrict__ attD,
    __hip_bfloat16* __restrict__ h1, float* __restrict__ a1s,
    float* __restrict__ a1d, const int* __restrict__ flags) {
    __shared__ __align__(16) char smem[33280];     // max(csr 3KB, mgemm 33KB)
    int tid = threadIdx.x;
    if (blockIdx.x < NB) {
        int* hist = (int*)smem;
        int* cur  = (int*)(smem + 1024);
        int* sd   = (int*)(smem + 2048);
        int bk = blockIdx.x;
        int n0 = bk * BSH;
        if (tid < 256) sd[tid] = (tid < NB) ? min(bcnt[tid], BCAP) : 0;
        __syncthreads();
        for (int off = 1; off < BSH; off <<= 1) {
            int t = 0;
            if (tid < 256 && tid >= off) t = sd[tid - off];
            __syncthreads();
            if (tid < 256) sd[tid] += t;
            __syncthreads();
        }
        int gb = (bk > 0) ? sd[bk - 1] : 0;
        if (bk == 0 && tid == 0) offs[NN] = sd[NB - 1];
        __syncthreads();
        int cnt = bcnt[bk]; if (cnt > BCAP) cnt = BCAP;
        const unsigned* bp = binned + (size_t)bk * BCAP;
        if (tid < 256) hist[tid] = 0;
        __syncthreads();
        for (int i = tid; i < cnt; i += 1024)
            atomicAdd(&hist[bp[i] & 255], 1);
        __syncthreads();
        int myh = (tid < 256) ? hist[tid] : 0;
        if (tid < 256) sd[tid] = myh;
        __syncthreads();
        for (int off = 1; off < BSH; off <<= 1) {
            int t = 0;
            if (tid < 256 && tid >= off) t = sd[tid - off];
            __syncthreads();
            if (tid < 256) sd[tid] += t;
            __syncthreads();
        }
        if (tid < 256) {
            int excl = sd[tid] - myh;
            cur[tid] = gb + excl;
            if (n0 + tid < NN) offs[n0 + tid] = gb + excl;
        }
        __syncthreads();
        for (int i = tid; i < cnt; i += 1024) {
            unsigned pk = bp[i];
            int pos = atomicAdd(&cur[pk & 255], 1);
            perm[pos] = (int)(pk >> 8);
        }
    } else {
        // ---- mgemm1 role: 4 sub-tiles of 64 nodes ----
        int fp32 = flags[0];
        unsigned short* hl = (unsigned short*)smem;          // 4 x 4096 ushort
        float* attSl = (float*)(smem + 32768);
        float* attDl = (float*)(smem + 32768 + 256);
        if (tid < 64) { attSl[tid] = loadF(attS, tid, fp32); attDl[tid] = loadF(attD, tid, fp32); }
        int sub = tid >> 8, t = tid & 255;
        int w = t >> 6, l = t & 63;
        int quad = l >> 4, lm = l & 15;
        int n0 = (blockIdx.x - NB) * 256 + sub * 64;
        unsigned short* hls = hl + sub * 4096;

        bf16x8 bfr[16];
        #pragma unroll
        for (int f = 0; f < 16; ++f)
            bfr[f] = *(const bf16x8*)(W1p + f * 512 + l * 8);

        int nodeA = n0 + w * 16 + lm;
        long long rowA = (nodeA < NN) ? nodeA : 0;     // clamp; garbage unused
        f32x4 acc[4];
        #pragma unroll
        for (int nt = 0; nt < 4; ++nt) acc[nt] = (f32x4){0.f, 0.f, 0.f, 0.f};

        #pragma unroll
        for (int kb = 0; kb < 4; ++kb) {
            bf16x8 af;
            if (!fp32) {
                af = *(const bf16x8*)((const unsigned short*)x + rowA * FIN + kb * 32 + quad * 8);
            } else {
                const float* xf = (const float*)x + rowA * FIN + kb * 32 + quad * 8;
                union { unsigned short s[8]; bf16x8 v; } tmp;
                #pragma unroll
                for (int j = 0; j < 8; ++j) tmp.s[j] = f2bfu(xf[j]);
                af = tmp.v;
            }
            #pragma unroll
            for (int nt = 0; nt < 4; ++nt)
                acc[nt] = __builtin_amdgcn_mfma_f32_16x16x32_bf16(af, bfr[kb * 4 + nt], acc[nt], 0, 0, 0);
        }

        #pragma unroll
        for (int nt = 0; nt < 4; ++nt) {
            #pragma unroll
            for (int r = 0; r < 4; ++r) {
                int nl = w * 16 + quad * 4 + r;
                int node = n0 + nl;
                int c = nt * 16 + lm;
                unsigned short hb = f2bfu(acc[nt][r]);
                hls[nl * 64 + c] = hb;
                if (node < NN) ((unsigned short*)h1)[(size_t)node * 64 + c] = hb;
            }
        }
        __syncthreads();
        // a1s/a1d per (node, head): 64 nodes x 8 heads = 512 pairs per sub
        #pragma unroll
        for (int pp = 0; pp < 2; ++pp) {
            int p = t + pp * 256;
            int nl = p >> 3, g = p & 7;
            int node = n0 + nl;
            float ss = 0.f, dd = 0.f;
            #pragma unroll
            for (int j = 0; j < 8; ++j) {
                float hv = b2f(hls[nl * 64 + g * 8 + j]);
                ss += hv * attSl[g * 8 + j];
                dd += hv * attDl[g * 8 + j];
            }
            if (node < NN) {
                a1s[(size_t)node * NH1 + g] = ss;
                a1d[(size_t)node * NH1 + g] = dd;
            }
        }
    }
}

// ---------------- Fused layer-1 agg + layer-2 GEMM + scalar projection ----------------
// R25 k_agg1f = R3/R19 verbatim (best measured: 51.5 us): 8-edge x 8-lane
// mapping, edge loop unrolled 2x with both batches' loads issued before
// consumption, plain __launch_bounds__(256) (VGPR 32, ~60% occupancy).
// CLOSED LINES for k_agg1f (all measured worse or null):
//   R4  sw-pipeline: compiler folds it (null).  R18 L2 half-split: +15% FETCH.
//   R22 4-dst interleave: 82us (addr-dep serial + imbalance + occupancy).
//   R23 unroll-4 @(256,2): 57.4us (occupancy 42% outweighs depth 12).
// k_agg1f sits at the L2-capacity FETCH floor (~90MB) at ~1.8 TB/s service.

#define HLP 72

__global__ __launch_bounds__(256) void k_agg1f(
    const int* __restrict__ offs, const int* __restrict__ perm,
    const __hip_bfloat16* __restrict__ h1, const float* __restrict__ a1s,
    const float* __restrict__ a1d, const void* __restrict__ b1,
    const unsigned short* __restrict__ W2p,
    const void* __restrict__ attS2, const void* __restrict__ attD2,
    const void* __restrict__ linW,
    float2* __restrict__ g2s, float* __restrict__ a2d,
    int n, const int* __restrict__ flags) {
    int fp32 = flags[0];
    __shared__ __align__(16) unsigned short hl[16 * HLP];   // 2.25 KB helu tile (bf16 bits)
    __shared__ float attSl[64], attDl[64];
    __shared__ float sp[16 * 4], dp[16 * 4], gp[16 * 4];
    int tid = threadIdx.x;
    if (tid < 64) { attSl[tid] = loadF(attS2, tid, fp32); attDl[tid] = loadF(attD2, tid, fp32); }
    int w = tid >> 6, c = tid & 63;
    int n0 = blockIdx.x * 16;
    const unsigned short* hu = (const unsigned short*)h1;

    // ---- phase 1: aggregation, 8-edge x 8-lane scheme, unroll-2 ----
    int g = c >> 3, q = c & 7;
    float b1r[8];
    #pragma unroll
    for (int k = 0; k < 8; ++k) b1r[k] = loadF(b1, q * 8 + k, fp32);

    for (int m = 0; m < 4; ++m) {
        int d = n0 + w * 4 + m;
        if (d < n) {
            int start = offs[d], end = offs[d + 1];
            float adl = a1d[(size_t)d * NH1 + q];
            float accv[8];
            #pragma unroll
            for (int k = 0; k < 8; ++k) accv[k] = 0.f;
            float den = 0.f;
            for (int i = start; i < end; i += 16) {
                int j0 = i + g, j1 = i + 8 + g;
                int jc0 = (j0 < end) ? j0 : (end - 1);
                int jc1 = (j1 < end) ? j1 : (end - 1);
                // batch-issue all loads for both 8-edge groups
                int sj0 = perm[jc0];
                int sj1 = perm[jc1];
                float as0 = a1s[(size_t)sj0 * NH1 + q];
                float as1 = a1s[(size_t)sj1 * NH1 + q];
                u16x8 hv0 = *(const u16x8*)(hu + (size_t)sj0 * 64 + q * 8);
                u16x8 hv1 = *(const u16x8*)(hu + (size_t)sj1 * 64 + q * 8);
                float e0 = as0 + adl;
                e0 = fmaxf(e0, 0.2f * e0);                   // leaky_relu(0.2)
                float p0 = (j0 < end) ? __expf(e0) : 0.f;
                float e1 = as1 + adl;
                e1 = fmaxf(e1, 0.2f * e1);
                float p1 = (j1 < end) ? __expf(e1) : 0.f;
                den += p0 + p1;
                #pragma unroll
                for (int k = 0; k < 8; ++k) {
                    accv[k] = fmaf(p0, b2f(hv0[k]), accv[k]);
                    accv[k] = fmaf(p1, b2f(hv1[k]), accv[k]);
                }
            }
            // tree-reduce across the 8 edge-slots (lane bits 3,4,5)
            #pragma unroll
            for (int k = 0; k < 8; ++k) {
                accv[k] += __shfl_xor(accv[k], 8, 64);
                accv[k] += __shfl_xor(accv[k], 16, 64);
                accv[k] += __shfl_xor(accv[k], 32, 64);
            }
            den += __shfl_xor(den, 8, 64);
            den += __shfl_xor(den, 16, 64);
            den += __shfl_xor(den, 32, 64);
            float rden = 1.f / (den + 1e-16f);
            if (g == 0) {                       // lanes 0..7 write 16B each
                unsigned pk4[4];
                #pragma unroll
                for (int k = 0; k < 4; ++k) {
                    float v0 = fmaf(accv[2 * k],     rden, b1r[2 * k]);
                    float v1 = fmaf(accv[2 * k + 1], rden, b1r[2 * k + 1]);
                    v0 = (v0 > 0.f) ? v0 : expm1f(v0);       // ELU
                    v1 = (v1 > 0.f) ? v1 : expm1f(v1);
                    pk4[k] = (unsigned)f2bfu(v0) | ((unsigned)f2bfu(v1) << 16);
                }
                *(uint4*)&hl[(w * 4 + m) * HLP + q * 8] =
                    make_uint4(pk4[0], pk4[1], pk4[2], pk4[3]);
            }
        }
    }
    __syncthreads();

    // ---- phase 2: h2 tile = hl @ W2 (wave w = col-tile w); g2/a2s/a2d epilogue ----
    int quad = c >> 4, lm = c & 15;
    bf16x8 bf0 = *(const bf16x8*)(W2p + (0 * 4 + w) * 512 + c * 8);
    bf16x8 bf1 = *(const bf16x8*)(W2p + (1 * 4 + w) * 512 + c * 8);
    bf16x8 af0 = *(const bf16x8*)(hl + lm * HLP + 0 * 32 + quad * 8);
    bf16x8 af1 = *(const bf16x8*)(hl + lm * HLP + 1 * 32 + quad * 8);
    f32x4 acc2 = (f32x4){0.f, 0.f, 0.f, 0.f};
    acc2 = __builtin_amdgcn_mfma_f32_16x16x32_bf16(af0, bf0, acc2, 0, 0, 0);
    acc2 = __builtin_amdgcn_mfma_f32_16x16x32_bf16(af1, bf1, acc2, 0, 0, 0);

    int cg = w * 16 + lm;                                // global output col
    float aSc = attSl[cg], aDc = attDl[cg];
    float lWc = loadF(linW, cg, fp32);
    #pragma unroll
    for (int r = 0; r < 4; ++r) {
        int nl = quad * 4 + r;
        unsigned short hb = f2bfu(acc2[r]);              // same rounding as before
        float hv = b2f(hb);
        float pvs = hv * aSc, pvd = hv * aDc, pvg = hv * lWc;
        pvs += __shfl_xor(pvs, 1, 64); pvd += __shfl_xor(pvd, 1, 64); pvg += __shfl_xor(pvg, 1, 64);
        pvs += __shfl_xor(pvs, 2, 64); pvd += __shfl_xor(pvd, 2, 64); pvg += __shfl_xor(pvg, 2, 64);
        pvs += __shfl_xor(pvs, 4, 64); pvd += __shfl_xor(pvd, 4, 64); pvg += __shfl_xor(pvg, 4, 64);
        pvs += __shfl_xor(pvs, 8, 64); pvd += __shfl_xor(pvd, 8, 64); pvg += __shfl_xor(pvg, 8, 64);
        if (lm == 0) { sp[nl * 4 + w] = pvs; dp[nl * 4 + w] = pvd; gp[nl * 4 + w] = pvg; }
    }
    __syncthreads();
    if (tid < 16) {
        int node = n0 + tid;
        if (node < n) {
            float ss = sp[tid * 4 + 0] + sp[tid * 4 + 1] + sp[tid * 4 + 2] + sp[tid * 4 + 3];
            float dd = dp[tid * 4 + 0] + dp[tid * 4 + 1] + dp[tid * 4 + 2] + dp[tid * 4 + 3];
            float gg = gp[tid * 4 + 0] + gp[tid * 4 + 1] + gp[tid * 4 + 2] + gp[tid * 4 + 3];
            g2s[node] = make_float2(ss, gg);
            a2d[node] = dd;
        }
    }
}

// ---------------- Layer 2 aggregation, 8-lane groups + unroll-2 (R25) ----------------
// R24's 8-lane mapping (+2us total) kept; this round adds the ONLY technique
// with a measured win on this loop shape (R3's unroll-2 batch-issue, +11% on
// k_agg1f): stride 16, both perm loads issued, then both g2s gathers, tail
// clamped to last. Dependent-chain trips per dst ~4 -> ~2.

__global__ __launch_bounds__(256) void k_agg2(
    const int* __restrict__ offs, const int* __restrict__ perm,
    const float2* __restrict__ g2s, const float* __restrict__ a2d,
    const void* __restrict__ b2, const void* __restrict__ linW,
    const void* __restrict__ linb,
    void* __restrict__ out, int n, const int* __restrict__ flags) {
    int fp32 = flags[0];
    int tid = threadIdx.x;
    int lane = tid & 63, wv = tid >> 6;
    int grp = lane >> 3, l8 = lane & 7;       // 8 groups of 8 lanes per wave
    // cst = dot(b2, linW) (uniform over dsts): one per-wave full reduce
    float cst = loadF(b2, lane, fp32) * loadF(linW, lane, fp32);
    #pragma unroll
    for (int off = 1; off < 64; off <<= 1) cst += __shfl_xor(cst, off, 64);
    cst += loadF(linb, 0, fp32);

    int d = blockIdx.x * 32 + wv * 8 + grp;
    if (d >= n) return;
    int start = offs[d], end = offs[d + 1];
    int last = end - 1;
    float ad = a2d[d];
    float acc = 0.f, den = 0.f;
    for (int i = start + l8; i < end; i += 16) {
        int j1 = i + 8;
        // batch-issue both perm loads, then both g2s gathers
        int s0 = perm[i];                      // i < end guaranteed
        int s1 = perm[min(j1, last)];
        float2 ag0 = g2s[s0];
        float2 ag1 = g2s[s1];
        float e0 = ag0.x + ad;
        e0 = fmaxf(e0, 0.2f * e0);                   // leaky_relu(0.2)
        float p0 = __expf(e0);
        float e1 = ag1.x + ad;
        e1 = fmaxf(e1, 0.2f * e1);
        float p1 = (j1 <= last) ? __expf(e1) : 0.f;
        acc = fmaf(p0, ag0.y, acc);
        acc = fmaf(p1, ag1.y, acc);
        den += p0 + p1;
    }
    // reduce within the 8-lane group (lane bits 0..2)
    acc += __shfl_xor(acc, 1, 64); den += __shfl_xor(den, 1, 64);
    acc += __shfl_xor(acc, 2, 64); den += __shfl_xor(den, 2, 64);
    acc += __shfl_xor(acc, 4, 64); den += __shfl_xor(den, 4, 64);
    if (l8 == 0) {
        float r = acc / (den + 1e-16f) + cst;
        if (fp32) ((float*)out)[d] = r;
        else      ((__hip_bfloat16*)out)[d] = __float2bfloat16(r);
    }
}

// ---------------- host launcher ----------------

static inline char* carve(char*& p, size_t bytes) {
    char* r = p;
    p += (bytes + 255) & ~size_t(255);
    return r;
}

extern "C" void kernel_launch(void* const* d_in, const int* in_sizes, int n_in,
                              void* d_out, int out_size, void* d_ws, size_t ws_size,
                              hipStream_t stream) {
    const void* x     = d_in[0];
    const void* ei    = d_in[1];
    const void* W1    = d_in[2];
    const void* attS1 = d_in[3];
    const void* attD1 = d_in[4];
    const void* b1    = d_in[5];
    const void* W2    = d_in[6];
    const void* attS2 = d_in[7];
    const void* attD2 = d_in[8];
    const void* b2    = d_in[9];
    const void* linW  = d_in[10];
    const void* linb  = d_in[11];

    int E    = in_sizes[1] / 2;
    int Etot = E + NN;

    // workspace layout (~25 MB)
    char* p = (char*)d_ws;
    int*   flags = (int*)carve(p, 256);
    int*   bcnt  = (int*)carve(p, (size_t)NB * 4);
    unsigned short* W1p = (unsigned short*)carve(p, 8192 * 2);
    unsigned short* W2p = (unsigned short*)carve(p, 4096 * 2);
    int*   offs  = (int*)carve(p, (size_t)(NN + 1) * 4);       // 200 KB
    int*   perm  = (int*)carve(p, (size_t)Etot * 4);           // 6.6 MB
    // binned has its own region (k_mid overlaps csr reads with mgemm writes)
    unsigned* binned = (unsigned*)carve(p, (size_t)NB * BCAP * 4);  // 7.43 MB
    float*    a1s    = (float*)carve(p, (size_t)NN * NH1 * 4);      // 1.6 MB
    float*    a1d    = (float*)carve(p, (size_t)NN * NH1 * 4);      // 1.6 MB
    __hip_bfloat16* h1 = (__hip_bfloat16*)carve(p, (size_t)NN * F1 * 2);  // 6.4 MB
    float2* g2s = (float2*)carve(p, (size_t)NN * 8);           // 400 KB (a2s, g2)
    float*  a2d = (float*)carve(p, (size_t)NN * 4);            // 200 KB

    hipMemsetAsync(bcnt, 0, (size_t)NB * 4, stream);

    int nbin = (Etot + 8191) / 8192;
    k_front<<<PREB + nbin, 1024, 0, stream>>>(x, ei, E, Etot, flags,
                                              W1, W2, W1p, W2p, bcnt, binned);
    k_mid<<<NB + MG1B, 1024, 0, stream>>>(bcnt, binned, offs, perm,
                                          x, W1p, attS1, attD1, h1, a1s, a1d, flags);
    k_agg1f<<<(NN + 15) / 16, 256, 0, stream>>>(offs, perm, h1, a1s, a1d, b1,
                                                W2p, attS2, attD2, linW, g2s, a2d, NN, flags);
    k_agg2<<<(NN + 31) / 32, 256, 0, stream>>>(offs, perm, g2s, a2d, b2, linW, linb, d_out, NN, flags);
}